// Round 7
// baseline (657.140 us; speedup 1.0000x reference)
//
#include <hip/hip_runtime.h>
#include <stdint.h>

#define NTOK 524288
#define ROWS 64
#define CHUNKS 64
#define NTHR 256
#define F4_PER_ROW (NTOK / 4)                 // 131072
#define F4_PER_CHUNK (F4_PER_ROW / CHUNKS)    // 2048
#define F4_PER_THR (F4_PER_CHUNK / NTHR)      // 8
#define NB1 2048                              // 16-bit level-1: exp[960,1024) x 32
#define B1BASE 30720                          // 960 << 5
#define BCAP 65536                            // per-row B1-candidate buffer cap
#define GCAP 8192
#define FB_CHUNKS 16

// ---- workspace layout (bytes) ----
#define OFF_H16  0u
#define OFF_H2   (OFF_H16 + ROWS * NB1 * 4u)           // 512 KiB
#define OFF_B1   (OFF_H2 + ROWS * 4096u * 4u)          // +1 MiB
#define OFF_CG   (OFF_B1 + 256u)
#define OFF_B2   (OFF_CG + 256u)
#define OFF_REM  (OFF_B2 + 256u)
#define OFF_IT   (OFF_REM + 256u)
#define OFF_BCNT (OFF_IT + 256u)
#define OFF_GCNT (OFF_BCNT + 256u)
#define OFF_T    (OFF_GCNT + 256u)                     // 8-aligned
#define OFF_ZERO_END (OFF_T + 512u)
#define OFF_TAB  OFF_ZERO_END                          // 64*112 doubles
#define OFF_BK   (OFF_TAB + ROWS * 112u * 8u)          // 32 MiB keys
#define OFF_BI   (OFF_BK + (size_t)ROWS * BCAP * 8u)   // 16 MiB idx
#define OFF_GKEY (OFF_BI + (size_t)ROWS * BCAP * 4u)   // 4 MiB fb keys
#define OFF_GIDX (OFF_GKEY + (size_t)ROWS * GCAP * 8u) // 2 MiB fb idx

__device__ __forceinline__ double clamp64(double x) {
  return fmin(fmax(x, 1.0e-3), 1.0 - 1.0e-3);
}

__device__ __forceinline__ unsigned compute_K(float ur) {
  float urf = fminf(fmaxf(ur, 1.0e-3f), 1.0f - 1.0e-3f);
  return (unsigned)(int)(urf * (float)NTOK);
}

// level-1 bucket: bits [62:47] = exponent(11b) + mantissa-top-5, rebased.
// All keys have exp in [985,1023) (min key >= 1e-3^3.75 ~ 2^-37.4), so no clamping
// in practice; clamp kept for safety.
__device__ __forceinline__ int bucket16(unsigned long long kb) {
  int b = (int)(unsigned)(kb >> 47) - B1BASE;
  return b < 0 ? 0 : (b > NB1 - 1 ? NB1 - 1 : b);
}

// ---- per-row dim factor tables: F = clamp(u)^(1/alpha), f64 ----
__global__ void k_tables(const float* __restrict__ comps, const int* __restrict__ idxp,
                         const float* __restrict__ uvs, const float* __restrict__ uts,
                         const float* __restrict__ uhs, const float* __restrict__ uws,
                         const float* __restrict__ uvt, const float* __restrict__ utt,
                         const float* __restrict__ uht, const float* __restrict__ uwt,
                         double* __restrict__ tabs) {
  int idx = idxp[0];
  double alpha[4];
  for (int d = 0; d < 4; ++d) alpha[d] = (double)comps[idx * 4 + d];
  for (int i = threadIdx.x; i < ROWS * 112; i += blockDim.x) {
    int row = i / 112, j = i % 112;
    int m = row >> 5, b = row & 31;
    int d, jj, dsz;
    if (j < 16)      { d = 0; jj = j;      dsz = 16; }
    else if (j < 48) { d = 1; jj = j - 16; dsz = 32; }
    else if (j < 80) { d = 2; jj = j - 48; dsz = 32; }
    else             { d = 3; jj = j - 80; dsz = 32; }
    const float* u;
    if (m == 0) u = (d == 0) ? uvs : (d == 1) ? uts : (d == 2) ? uhs : uws;
    else        u = (d == 0) ? uvt : (d == 1) ? utt : (d == 2) ? uht : uwt;
    double x = clamp64((double)u[b * dsz + jj]);
    double a = alpha[d];
    double f;
    if (a == 1.0)      f = x;
    else if (a == 2.0) f = sqrt(x);
    else if (a == 4.0) f = sqrt(sqrt(x));
    else               f = pow(x, 1.0 / a);
    tabs[row * 112 + j] = f;
  }
}

// ---- pass 1: 2048-bucket level-1 histogram (low contention: mode bucket ~1%) ----
__global__ void k_hist16(const float* __restrict__ u0s, const float* __restrict__ u0t,
                         const double* __restrict__ tabs, unsigned int* __restrict__ h16) {
  __shared__ double tb[112];
  __shared__ unsigned int h[NB1];
  int row = blockIdx.x / CHUNKS, chunk = blockIdx.x % CHUNKS;
  for (int i = threadIdx.x; i < 112; i += blockDim.x) tb[i] = tabs[row * 112 + i];
  for (int i = threadIdx.x; i < NB1; i += blockDim.x) h[i] = 0;
  __syncthreads();
  int m = row >> 5, b = row & 31;
  const float4* u0 = reinterpret_cast<const float4*>((m ? u0t : u0s) + (size_t)b * NTOK);
  int base = chunk * F4_PER_CHUNK;
  for (int it = 0; it < F4_PER_THR; ++it) {
    int f4 = base + it * NTHR + threadIdx.x;
    float4 x = u0[f4];
    int n0 = f4 * 4;
    int w0 = n0 & 31, hh = (n0 >> 5) & 31, tt = (n0 >> 10) & 31, vv = n0 >> 15;
    double g = tb[vv] * tb[16 + tt] * tb[48 + hh];
    double k0 = clamp64((double)x.x) * (g * tb[80 + w0 + 0]);
    double k1 = clamp64((double)x.y) * (g * tb[80 + w0 + 1]);
    double k2 = clamp64((double)x.z) * (g * tb[80 + w0 + 2]);
    double k3 = clamp64((double)x.w) * (g * tb[80 + w0 + 3]);
    atomicAdd(&h[bucket16((unsigned long long)__double_as_longlong(k0))], 1u);
    atomicAdd(&h[bucket16((unsigned long long)__double_as_longlong(k1))], 1u);
    atomicAdd(&h[bucket16((unsigned long long)__double_as_longlong(k2))], 1u);
    atomicAdd(&h[bucket16((unsigned long long)__double_as_longlong(k3))], 1u);
  }
  __syncthreads();
  for (int i = threadIdx.x; i < NB1; i += blockDim.x) {
    unsigned c = h[i];
    if (c) atomicAdd(&h16[row * NB1 + i], c);
  }
}

// ---- scan level-1: one block/row; B1 = bucket holding K-th largest; cG = count above ----
__global__ __launch_bounds__(256) void k_scan16(const unsigned int* __restrict__ h16,
                                                const float* __restrict__ urs,
                                                const float* __restrict__ urt,
                                                int* __restrict__ sB1, int* __restrict__ sCG) {
  __shared__ unsigned suf[256];
  __shared__ int best;
  int row = blockIdx.x;
  int t = threadIdx.x;
  const unsigned* h = h16 + row * NB1;
  unsigned loc[8]; unsigned own = 0;
#pragma unroll
  for (int i = 0; i < 8; ++i) { loc[i] = h[t * 8 + i]; own += loc[i]; }
  suf[t] = own;
  if (t == 0) best = -1;
  __syncthreads();
  for (int off = 1; off < 256; off <<= 1) {
    unsigned add = (t + off < 256) ? suf[t + off] : 0u;
    __syncthreads();
    suf[t] += add;
    __syncthreads();
  }
  int m = row >> 5;
  unsigned K = compute_K(m ? urt[0] : urs[0]);
  unsigned above = suf[t] - own;
  int cand = -1;
  unsigned cum = above;
  for (int i = 7; i >= 0; --i) {
    if (cum + loc[i] >= K) { cand = t * 8 + i; break; }
    cum += loc[i];
  }
  if (cand >= 0) atomicMax(&best, cand);
  __syncthreads();
  int bb = best;
  if (bb >= 0 && (bb >> 3) == t) {
    unsigned cg = above;
    for (int i = 7; i > (bb & 7); --i) cg += loc[i];
    sB1[row] = bb;
    sCG[row] = (int)cg;
  }
}

// ---- pass 2 (fused): gather B1 members (~5K/row) + their [50:39] refine-hist ----
__global__ void k_gather2(const float* __restrict__ u0s, const float* __restrict__ u0t,
                          const double* __restrict__ tabs, const int* __restrict__ sB1,
                          unsigned int* __restrict__ gh2, unsigned int* __restrict__ bcnt,
                          unsigned long long* __restrict__ bk, unsigned int* __restrict__ bi) {
  __shared__ double tb[112];
  __shared__ unsigned int h[4096];
  int row = blockIdx.x / CHUNKS, chunk = blockIdx.x % CHUNKS;
  for (int i = threadIdx.x; i < 112; i += blockDim.x) tb[i] = tabs[row * 112 + i];
  for (int i = threadIdx.x; i < 4096; i += blockDim.x) h[i] = 0;
  __syncthreads();
  int b1 = sB1[row];
  int m = row >> 5, b = row & 31;
  const float4* u0 = reinterpret_cast<const float4*>((m ? u0t : u0s) + (size_t)b * NTOK);
  int base = chunk * F4_PER_CHUNK;
  for (int it = 0; it < F4_PER_THR; ++it) {
    int f4 = base + it * NTHR + threadIdx.x;
    float4 x = u0[f4];
    int n0 = f4 * 4;
    int w0 = n0 & 31, hh = (n0 >> 5) & 31, tt = (n0 >> 10) & 31, vv = n0 >> 15;
    double g = tb[vv] * tb[16 + tt] * tb[48 + hh];
    double ks[4];
    ks[0] = clamp64((double)x.x) * (g * tb[80 + w0 + 0]);
    ks[1] = clamp64((double)x.y) * (g * tb[80 + w0 + 1]);
    ks[2] = clamp64((double)x.z) * (g * tb[80 + w0 + 2]);
    ks[3] = clamp64((double)x.w) * (g * tb[80 + w0 + 3]);
#pragma unroll
    for (int c = 0; c < 4; ++c) {
      unsigned long long kb = (unsigned long long)__double_as_longlong(ks[c]);
      if (bucket16(kb) == b1) {
        atomicAdd(&h[(unsigned)(kb >> 39) & 0xFFFu], 1u);   // hist complete regardless of cap
        unsigned pos = atomicAdd(&bcnt[row], 1u);
        if (pos < BCAP) {
          bk[(size_t)row * BCAP + pos] = kb;
          bi[(size_t)row * BCAP + pos] = (unsigned)(n0 + c);
        }
      }
    }
  }
  __syncthreads();
  for (int i = threadIdx.x; i < 4096; i += blockDim.x) {
    unsigned c = h[i];
    if (c) atomicAdd(&gh2[row * 4096 + i], c);
  }
}

// ---- scan level-2: B2 + remaining count (exact; gh2 counts ALL B1 members) ----
__global__ __launch_bounds__(256) void k_scan2(const unsigned int* __restrict__ gh2,
                                               const float* __restrict__ urs,
                                               const float* __restrict__ urt,
                                               const int* __restrict__ sCG,
                                               int* __restrict__ sB2, int* __restrict__ sREM) {
  __shared__ unsigned suf[256];
  __shared__ int best;
  int row = blockIdx.x;
  int t = threadIdx.x;
  const unsigned* h = gh2 + row * 4096;
  unsigned loc[16]; unsigned own = 0;
#pragma unroll
  for (int i = 0; i < 16; ++i) { loc[i] = h[t * 16 + i]; own += loc[i]; }
  suf[t] = own;
  if (t == 0) best = -1;
  __syncthreads();
  for (int off = 1; off < 256; off <<= 1) {
    unsigned add = (t + off < 256) ? suf[t + off] : 0u;
    __syncthreads();
    suf[t] += add;
    __syncthreads();
  }
  int m = row >> 5;
  unsigned K = compute_K(m ? urt[0] : urs[0]);
  unsigned K2 = K - (unsigned)sCG[row];   // >= 1
  unsigned above = suf[t] - own;
  int cand = -1;
  unsigned cum = above;
  for (int i = 15; i >= 0; --i) {
    if (cum + loc[i] >= K2) { cand = t * 16 + i; break; }
    cum += loc[i];
  }
  if (cand >= 0) atomicMax(&best, cand);
  __syncthreads();
  int bb = best;
  if (bb >= 0 && (bb >> 4) == t) {
    unsigned a2 = above;
    for (int i = 15; i > (bb & 15); --i) a2 += loc[i];
    sB2[row] = bb;
    sREM[row] = (int)(K2 - a2);
  }
}

// ---- fallback gather: only if the B1 buffer overflowed (expected never) ----
__global__ void k_gather_fb(const float* __restrict__ u0s, const float* __restrict__ u0t,
                            const double* __restrict__ tabs,
                            const int* __restrict__ sB1, const int* __restrict__ sB2,
                            const unsigned int* __restrict__ bcnt,
                            unsigned int* __restrict__ gcnt,
                            unsigned long long* __restrict__ gkey, unsigned int* __restrict__ gidx) {
  int row = blockIdx.x / FB_CHUNKS, chunk = blockIdx.x % FB_CHUNKS;
  if (bcnt[row] <= BCAP) return;
  __shared__ double tb[112];
  for (int i = threadIdx.x; i < 112; i += blockDim.x) tb[i] = tabs[row * 112 + i];
  __syncthreads();
  int b1 = sB1[row];
  unsigned b2 = (unsigned)sB2[row];
  int m = row >> 5, b = row & 31;
  const float4* u0 = reinterpret_cast<const float4*>((m ? u0t : u0s) + (size_t)b * NTOK);
  int base = chunk * (F4_PER_ROW / FB_CHUNKS);
  for (int it = 0; it < F4_PER_ROW / FB_CHUNKS / NTHR; ++it) {
    int f4 = base + it * NTHR + threadIdx.x;
    float4 x = u0[f4];
    int n0 = f4 * 4;
    int w0 = n0 & 31, hh = (n0 >> 5) & 31, tt = (n0 >> 10) & 31, vv = n0 >> 15;
    double g = tb[vv] * tb[16 + tt] * tb[48 + hh];
    double ks[4];
    ks[0] = clamp64((double)x.x) * (g * tb[80 + w0 + 0]);
    ks[1] = clamp64((double)x.y) * (g * tb[80 + w0 + 1]);
    ks[2] = clamp64((double)x.z) * (g * tb[80 + w0 + 2]);
    ks[3] = clamp64((double)x.w) * (g * tb[80 + w0 + 3]);
#pragma unroll
    for (int c = 0; c < 4; ++c) {
      unsigned long long kb = (unsigned long long)__double_as_longlong(ks[c]);
      if (bucket16(kb) == b1 && (((unsigned)(kb >> 39)) & 0xFFFu) == b2) {
        unsigned pos = atomicAdd(&gcnt[row], 1u);
        if (pos < GCAP) {
          gkey[(size_t)row * GCAP + pos] = kb;
          gidx[(size_t)row * GCAP + pos] = (unsigned)(n0 + c);
        }
      }
    }
  }
}

// ---- select: filter buffer by B2 (typ. a few elements), sort, pick REM-th ----
__global__ __launch_bounds__(1024) void k_select(const unsigned long long* __restrict__ bk,
                                                 const unsigned int* __restrict__ bi,
                                                 const unsigned int* __restrict__ bcnt,
                                                 const unsigned long long* __restrict__ gkey,
                                                 const unsigned int* __restrict__ gidx,
                                                 const unsigned int* __restrict__ gcnt,
                                                 const int* __restrict__ sB2,
                                                 const int* __restrict__ sREM,
                                                 unsigned long long* __restrict__ sT,
                                                 int* __restrict__ sIT) {
  __shared__ unsigned long long k[GCAP];
  __shared__ unsigned int ix[GCAP];
  __shared__ unsigned int lcnt;
  int row = blockIdx.x;
  if (threadIdx.x == 0) lcnt = 0;
  __syncthreads();
  unsigned cnt1 = bcnt[row];
  unsigned n_r;
  if (cnt1 <= BCAP) {
    unsigned b2 = (unsigned)sB2[row];
    for (unsigned i = threadIdx.x; i < cnt1; i += blockDim.x) {
      unsigned long long kb = bk[(size_t)row * BCAP + i];
      if ((((unsigned)(kb >> 39)) & 0xFFFu) == b2) {
        unsigned p = atomicAdd(&lcnt, 1u);
        if (p < GCAP) { k[p] = kb; ix[p] = bi[(size_t)row * BCAP + i]; }
      }
    }
    __syncthreads();
    n_r = lcnt; if (n_r > GCAP) n_r = GCAP;
  } else {
    n_r = gcnt[row];
    if (n_r > GCAP) n_r = GCAP;
    for (unsigned i = threadIdx.x; i < n_r; i += blockDim.x) {
      k[i] = gkey[(size_t)row * GCAP + i];
      ix[i] = gidx[(size_t)row * GCAP + i];
    }
    __syncthreads();
  }
  unsigned n2 = 2;
  while (n2 < n_r) n2 <<= 1;
  for (unsigned i = threadIdx.x; i < n2; i += blockDim.x) {
    if (i >= n_r) { k[i] = 0ULL; ix[i] = 0xFFFFFFFFu; }
  }
  __syncthreads();
  for (unsigned kk = 2; kk <= n2; kk <<= 1) {
    for (unsigned j = kk >> 1; j > 0; j >>= 1) {
      for (int i = threadIdx.x; i < (int)n2; i += blockDim.x) {
        int pj = i ^ (int)j;
        if (pj > i) {
          unsigned long long k1 = k[i], k2 = k[pj];
          unsigned i1 = ix[i], i2 = ix[pj];
          bool bef = (k1 > k2) || (k1 == k2 && i1 < i2);
          bool dirAsc = ((i & (int)kk) == 0);
          if (bef != dirAsc) { k[i] = k2; k[pj] = k1; ix[i] = i2; ix[pj] = i1; }
        }
      }
      __syncthreads();
    }
  }
  if (threadIdx.x == 0) {
    int rem = sREM[row];
    if (rem < 1) rem = 1;
    if ((unsigned)rem > n_r) rem = (int)n_r;
    sT[row] = k[rem - 1];
    sIT[row] = (int)ix[rem - 1];
  }
}

// ---- final: write masks as int32 0/1 ----
__global__ void k_final(const float* __restrict__ u0s, const float* __restrict__ u0t,
                        const double* __restrict__ tabs,
                        const unsigned long long* __restrict__ sT, const int* __restrict__ sIT,
                        int* __restrict__ out) {
  __shared__ double tb[112];
  int row = blockIdx.x / CHUNKS, chunk = blockIdx.x % CHUNKS;
  for (int i = threadIdx.x; i < 112; i += blockDim.x) tb[i] = tabs[row * 112 + i];
  __syncthreads();
  unsigned long long T = sT[row];
  int IT = sIT[row];
  int m = row >> 5, b = row & 31;
  const float4* u0 = reinterpret_cast<const float4*>((m ? u0t : u0s) + (size_t)b * NTOK);
  int4* o = reinterpret_cast<int4*>(out + (size_t)row * NTOK);
  int base = chunk * F4_PER_CHUNK;
  for (int it = 0; it < F4_PER_THR; ++it) {
    int f4 = base + it * NTHR + threadIdx.x;
    float4 x = u0[f4];
    int n0 = f4 * 4;
    int w0 = n0 & 31, hh = (n0 >> 5) & 31, tt = (n0 >> 10) & 31, vv = n0 >> 15;
    double g = tb[vv] * tb[16 + tt] * tb[48 + hh];
    unsigned long long kb0 = (unsigned long long)__double_as_longlong(clamp64((double)x.x) * (g * tb[80 + w0 + 0]));
    unsigned long long kb1 = (unsigned long long)__double_as_longlong(clamp64((double)x.y) * (g * tb[80 + w0 + 1]));
    unsigned long long kb2 = (unsigned long long)__double_as_longlong(clamp64((double)x.z) * (g * tb[80 + w0 + 2]));
    unsigned long long kb3 = (unsigned long long)__double_as_longlong(clamp64((double)x.w) * (g * tb[80 + w0 + 3]));
    int4 r;
    r.x = (kb0 > T || (kb0 == T && (n0 + 0) <= IT)) ? 1 : 0;
    r.y = (kb1 > T || (kb1 == T && (n0 + 1) <= IT)) ? 1 : 0;
    r.z = (kb2 > T || (kb2 == T && (n0 + 2) <= IT)) ? 1 : 0;
    r.w = (kb3 > T || (kb3 == T && (n0 + 3) <= IT)) ? 1 : 0;
    o[f4] = r;
  }
}

extern "C" void kernel_launch(void* const* d_in, const int* in_sizes, int n_in,
                              void* d_out, int out_size, void* d_ws, size_t ws_size,
                              hipStream_t stream) {
  const float* comps = (const float*)d_in[0];
  const float* urs   = (const float*)d_in[1];
  const float* urt   = (const float*)d_in[2];
  const float* u0s   = (const float*)d_in[3];
  const float* u0t   = (const float*)d_in[4];
  const float* uvs   = (const float*)d_in[5];
  const float* uts   = (const float*)d_in[6];
  const float* uhs   = (const float*)d_in[7];
  const float* uws   = (const float*)d_in[8];
  const float* uvt   = (const float*)d_in[9];
  const float* utt   = (const float*)d_in[10];
  const float* uht   = (const float*)d_in[11];
  const float* uwt   = (const float*)d_in[12];
  const int*   idxp  = (const int*)d_in[13];
  int* out = (int*)d_out;

  char* ws = (char*)d_ws;
  unsigned int*       h16  = (unsigned int*)(ws + OFF_H16);
  unsigned int*       gh2  = (unsigned int*)(ws + OFF_H2);
  int*                sB1  = (int*)(ws + OFF_B1);
  int*                sCG  = (int*)(ws + OFF_CG);
  int*                sB2  = (int*)(ws + OFF_B2);
  int*                sREM = (int*)(ws + OFF_REM);
  int*                sIT  = (int*)(ws + OFF_IT);
  unsigned int*       bcnt = (unsigned int*)(ws + OFF_BCNT);
  unsigned int*       gcnt = (unsigned int*)(ws + OFF_GCNT);
  unsigned long long* sT   = (unsigned long long*)(ws + OFF_T);
  double*             tabs = (double*)(ws + OFF_TAB);
  unsigned long long* bk   = (unsigned long long*)(ws + OFF_BK);
  unsigned int*       bi   = (unsigned int*)(ws + OFF_BI);
  unsigned long long* gkey = (unsigned long long*)(ws + OFF_GKEY);
  unsigned int*       gidx = (unsigned int*)(ws + OFF_GIDX);

  // zero hists + counters (ws is poisoned 0xAA before every call)
  hipMemsetAsync(d_ws, 0, OFF_ZERO_END, stream);

  k_tables<<<1, 256, 0, stream>>>(comps, idxp, uvs, uts, uhs, uws, uvt, utt, uht, uwt, tabs);
  k_hist16<<<ROWS * CHUNKS, NTHR, 0, stream>>>(u0s, u0t, tabs, h16);
  k_scan16<<<ROWS, 256, 0, stream>>>(h16, urs, urt, sB1, sCG);
  k_gather2<<<ROWS * CHUNKS, NTHR, 0, stream>>>(u0s, u0t, tabs, sB1, gh2, bcnt, bk, bi);
  k_scan2<<<ROWS, 256, 0, stream>>>(gh2, urs, urt, sCG, sB2, sREM);
  k_gather_fb<<<ROWS * FB_CHUNKS, NTHR, 0, stream>>>(u0s, u0t, tabs, sB1, sB2, bcnt, gcnt, gkey, gidx);
  k_select<<<ROWS, 1024, 0, stream>>>(bk, bi, bcnt, gkey, gidx, gcnt, sB2, sREM, sT, sIT);
  k_final<<<ROWS * CHUNKS, NTHR, 0, stream>>>(u0s, u0t, tabs, sT, sIT, out);
}

// Round 9
// 370.216 us; speedup vs baseline: 1.7750x; 1.7750x over previous
//
#include <hip/hip_runtime.h>
#include <stdint.h>

#define NTOK 524288
#define ROWS 64
#define CHUNKS 64
#define NTHR 256
#define F4_PER_ROW (NTOK / 4)                 // 131072
#define F4_PER_CHUNK (F4_PER_ROW / CHUNKS)    // 2048
#define F4_PER_THR (F4_PER_CHUNK / NTHR)      // 8
#define NB1 2048                              // 16-bit level-1: exp[960,1024) x 32
#define B1BASE 30720                          // 960 << 5
#define BCAP 65536                            // per-row B1-candidate buffer cap
#define GCAP 8192
#define FB_CHUNKS 16
#define STAGECAP 512                          // per-block LDS staging (expected ~107)

// ---- workspace layout (bytes) ----
#define OFF_H16  0u
#define OFF_H2   (OFF_H16 + ROWS * NB1 * 4u)           // 512 KiB
#define OFF_B1   (OFF_H2 + ROWS * 4096u * 4u)          // +1 MiB
#define OFF_CG   (OFF_B1 + 256u)
#define OFF_B2   (OFF_CG + 256u)
#define OFF_REM  (OFF_B2 + 256u)
#define OFF_IT   (OFF_REM + 256u)
#define OFF_BCNT (OFF_IT + 256u)
#define OFF_GCNT (OFF_BCNT + 256u)
#define OFF_T    (OFF_GCNT + 256u)                     // 8-aligned
#define OFF_ZERO_END (OFF_T + 512u)
#define OFF_TAB  OFF_ZERO_END                          // 64*112 doubles
#define OFF_BK   (OFF_TAB + ROWS * 112u * 8u)          // 32 MiB keys
#define OFF_BI   (OFF_BK + (size_t)ROWS * BCAP * 8u)   // 16 MiB idx
#define OFF_GKEY (OFF_BI + (size_t)ROWS * BCAP * 4u)   // 4 MiB fb keys
#define OFF_GIDX (OFF_GKEY + (size_t)ROWS * GCAP * 8u) // 2 MiB fb idx

__device__ __forceinline__ double clamp64(double x) {
  return fmin(fmax(x, 1.0e-3), 1.0 - 1.0e-3);
}

__device__ __forceinline__ unsigned compute_K(float ur) {
  float urf = fminf(fmaxf(ur, 1.0e-3f), 1.0f - 1.0e-3f);
  return (unsigned)(int)(urf * (float)NTOK);
}

// level-1 bucket: bits [62:47] = exponent(11b) + mantissa-top-5, rebased.
__device__ __forceinline__ int bucket16(unsigned long long kb) {
  int b = (int)(unsigned)(kb >> 47) - B1BASE;
  return b < 0 ? 0 : (b > NB1 - 1 ? NB1 - 1 : b);
}

// ---- per-row dim factor tables: F = clamp(u)^(1/alpha), f64 ----
__global__ void k_tables(const float* __restrict__ comps, const int* __restrict__ idxp,
                         const float* __restrict__ uvs, const float* __restrict__ uts,
                         const float* __restrict__ uhs, const float* __restrict__ uws,
                         const float* __restrict__ uvt, const float* __restrict__ utt,
                         const float* __restrict__ uht, const float* __restrict__ uwt,
                         double* __restrict__ tabs) {
  int idx = idxp[0];
  double alpha[4];
  for (int d = 0; d < 4; ++d) alpha[d] = (double)comps[idx * 4 + d];
  for (int i = threadIdx.x; i < ROWS * 112; i += blockDim.x) {
    int row = i / 112, j = i % 112;
    int m = row >> 5, b = row & 31;
    int d, jj, dsz;
    if (j < 16)      { d = 0; jj = j;      dsz = 16; }
    else if (j < 48) { d = 1; jj = j - 16; dsz = 32; }
    else if (j < 80) { d = 2; jj = j - 48; dsz = 32; }
    else             { d = 3; jj = j - 80; dsz = 32; }
    const float* u;
    if (m == 0) u = (d == 0) ? uvs : (d == 1) ? uts : (d == 2) ? uhs : uws;
    else        u = (d == 0) ? uvt : (d == 1) ? utt : (d == 2) ? uht : uwt;
    double x = clamp64((double)u[b * dsz + jj]);
    double a = alpha[d];
    double f;
    if (a == 1.0)      f = x;
    else if (a == 2.0) f = sqrt(x);
    else if (a == 4.0) f = sqrt(sqrt(x));
    else               f = pow(x, 1.0 / a);
    tabs[row * 112 + j] = f;
  }
}

// ---- pass 1: 2048-bucket level-1 histogram (low contention: mode bucket ~1%) ----
__global__ void k_hist16(const float* __restrict__ u0s, const float* __restrict__ u0t,
                         const double* __restrict__ tabs, unsigned int* __restrict__ h16) {
  __shared__ double tb[112];
  __shared__ unsigned int h[NB1];
  int row = blockIdx.x / CHUNKS, chunk = blockIdx.x % CHUNKS;
  for (int i = threadIdx.x; i < 112; i += blockDim.x) tb[i] = tabs[row * 112 + i];
  for (int i = threadIdx.x; i < NB1; i += blockDim.x) h[i] = 0;
  __syncthreads();
  int m = row >> 5, b = row & 31;
  const float4* u0 = reinterpret_cast<const float4*>((m ? u0t : u0s) + (size_t)b * NTOK);
  int base = chunk * F4_PER_CHUNK;
  for (int it = 0; it < F4_PER_THR; ++it) {
    int f4 = base + it * NTHR + threadIdx.x;
    float4 x = u0[f4];
    int n0 = f4 * 4;
    int w0 = n0 & 31, hh = (n0 >> 5) & 31, tt = (n0 >> 10) & 31, vv = n0 >> 15;
    double g = tb[vv] * tb[16 + tt] * tb[48 + hh];
    double k0 = clamp64((double)x.x) * (g * tb[80 + w0 + 0]);
    double k1 = clamp64((double)x.y) * (g * tb[80 + w0 + 1]);
    double k2 = clamp64((double)x.z) * (g * tb[80 + w0 + 2]);
    double k3 = clamp64((double)x.w) * (g * tb[80 + w0 + 3]);
    atomicAdd(&h[bucket16((unsigned long long)__double_as_longlong(k0))], 1u);
    atomicAdd(&h[bucket16((unsigned long long)__double_as_longlong(k1))], 1u);
    atomicAdd(&h[bucket16((unsigned long long)__double_as_longlong(k2))], 1u);
    atomicAdd(&h[bucket16((unsigned long long)__double_as_longlong(k3))], 1u);
  }
  __syncthreads();
  for (int i = threadIdx.x; i < NB1; i += blockDim.x) {
    unsigned c = h[i];
    if (c) atomicAdd(&h16[row * NB1 + i], c);
  }
}

// ---- scan level-1: one block/row; B1 = bucket holding K-th largest; cG = count above ----
__global__ __launch_bounds__(256) void k_scan16(const unsigned int* __restrict__ h16,
                                                const float* __restrict__ urs,
                                                const float* __restrict__ urt,
                                                int* __restrict__ sB1, int* __restrict__ sCG) {
  __shared__ unsigned suf[256];
  __shared__ int best;
  int row = blockIdx.x;
  int t = threadIdx.x;
  const unsigned* h = h16 + row * NB1;
  unsigned loc[8]; unsigned own = 0;
#pragma unroll
  for (int i = 0; i < 8; ++i) { loc[i] = h[t * 8 + i]; own += loc[i]; }
  suf[t] = own;
  if (t == 0) best = -1;
  __syncthreads();
  for (int off = 1; off < 256; off <<= 1) {
    unsigned add = (t + off < 256) ? suf[t + off] : 0u;
    __syncthreads();
    suf[t] += add;
    __syncthreads();
  }
  int m = row >> 5;
  unsigned K = compute_K(m ? urt[0] : urs[0]);
  unsigned above = suf[t] - own;
  int cand = -1;
  unsigned cum = above;
  for (int i = 7; i >= 0; --i) {
    if (cum + loc[i] >= K) { cand = t * 8 + i; break; }
    cum += loc[i];
  }
  if (cand >= 0) atomicMax(&best, cand);
  __syncthreads();
  int bb = best;
  if (bb >= 0 && (bb >> 3) == t) {
    unsigned cg = above;
    for (int i = 7; i > (bb & 7); --i) cg += loc[i];
    sB1[row] = bb;
    sCG[row] = (int)cg;
  }
}

// ---- pass 2 (fused): gather B1 members + [50:39] refine-hist; LDS-staged append ----
__global__ void k_gather2(const float* __restrict__ u0s, const float* __restrict__ u0t,
                          const double* __restrict__ tabs, const int* __restrict__ sB1,
                          unsigned int* __restrict__ gh2, unsigned int* __restrict__ bcnt,
                          unsigned long long* __restrict__ bk, unsigned int* __restrict__ bi) {
  __shared__ double tb[112];
  __shared__ unsigned int h[4096];
  __shared__ unsigned long long sk[STAGECAP];
  __shared__ unsigned int si[STAGECAP];
  __shared__ unsigned int scnt, sbase;
  int row = blockIdx.x / CHUNKS, chunk = blockIdx.x % CHUNKS;
  for (int i = threadIdx.x; i < 112; i += blockDim.x) tb[i] = tabs[row * 112 + i];
  for (int i = threadIdx.x; i < 4096; i += blockDim.x) h[i] = 0;
  if (threadIdx.x == 0) scnt = 0;
  __syncthreads();
  int b1 = sB1[row];
  int m = row >> 5, b = row & 31;
  const float4* u0 = reinterpret_cast<const float4*>((m ? u0t : u0s) + (size_t)b * NTOK);
  int base = chunk * F4_PER_CHUNK;
  for (int it = 0; it < F4_PER_THR; ++it) {
    int f4 = base + it * NTHR + threadIdx.x;
    float4 x = u0[f4];
    int n0 = f4 * 4;
    int w0 = n0 & 31, hh = (n0 >> 5) & 31, tt = (n0 >> 10) & 31, vv = n0 >> 15;
    double g = tb[vv] * tb[16 + tt] * tb[48 + hh];
    double ks[4];
    ks[0] = clamp64((double)x.x) * (g * tb[80 + w0 + 0]);
    ks[1] = clamp64((double)x.y) * (g * tb[80 + w0 + 1]);
    ks[2] = clamp64((double)x.z) * (g * tb[80 + w0 + 2]);
    ks[3] = clamp64((double)x.w) * (g * tb[80 + w0 + 3]);
#pragma unroll
    for (int c = 0; c < 4; ++c) {
      unsigned long long kb = (unsigned long long)__double_as_longlong(ks[c]);
      if (bucket16(kb) == b1) {
        atomicAdd(&h[(unsigned)(kb >> 39) & 0xFFFu], 1u);   // hist complete regardless of caps
        unsigned p = atomicAdd(&scnt, 1u);                  // LDS atomic (cheap)
        if (p < STAGECAP) { sk[p] = kb; si[p] = (unsigned)(n0 + c); }
        else {  // statistically never: direct global append
          unsigned gp = atomicAdd(&bcnt[row], 1u);
          if (gp < BCAP) {
            bk[(size_t)row * BCAP + gp] = kb;
            bi[(size_t)row * BCAP + gp] = (unsigned)(n0 + c);
          }
        }
      }
    }
  }
  __syncthreads();
  unsigned nst = scnt; if (nst > STAGECAP) nst = STAGECAP;
  if (threadIdx.x == 0) sbase = atomicAdd(&bcnt[row], nst);  // ONE reservation per block
  __syncthreads();
  unsigned bs = sbase;
  for (unsigned i = threadIdx.x; i < nst; i += blockDim.x) {
    unsigned gp = bs + i;
    if (gp < BCAP) {
      bk[(size_t)row * BCAP + gp] = sk[i];
      bi[(size_t)row * BCAP + gp] = si[i];
    }
  }
  for (int i = threadIdx.x; i < 4096; i += blockDim.x) {
    unsigned c = h[i];
    if (c) atomicAdd(&gh2[row * 4096 + i], c);
  }
}

// ---- scan level-2: B2 + remaining count (exact; gh2 counts ALL B1 members) ----
__global__ __launch_bounds__(256) void k_scan2(const unsigned int* __restrict__ gh2,
                                               const float* __restrict__ urs,
                                               const float* __restrict__ urt,
                                               const int* __restrict__ sCG,
                                               int* __restrict__ sB2, int* __restrict__ sREM) {
  __shared__ unsigned suf[256];
  __shared__ int best;
  int row = blockIdx.x;
  int t = threadIdx.x;
  const unsigned* h = gh2 + row * 4096;
  unsigned loc[16]; unsigned own = 0;
#pragma unroll
  for (int i = 0; i < 16; ++i) { loc[i] = h[t * 16 + i]; own += loc[i]; }
  suf[t] = own;
  if (t == 0) best = -1;
  __syncthreads();
  for (int off = 1; off < 256; off <<= 1) {
    unsigned add = (t + off < 256) ? suf[t + off] : 0u;
    __syncthreads();
    suf[t] += add;
    __syncthreads();
  }
  int m = row >> 5;
  unsigned K = compute_K(m ? urt[0] : urs[0]);
  unsigned K2 = K - (unsigned)sCG[row];   // >= 1
  unsigned above = suf[t] - own;
  int cand = -1;
  unsigned cum = above;
  for (int i = 15; i >= 0; --i) {
    if (cum + loc[i] >= K2) { cand = t * 16 + i; break; }
    cum += loc[i];
  }
  if (cand >= 0) atomicMax(&best, cand);
  __syncthreads();
  int bb = best;
  if (bb >= 0 && (bb >> 4) == t) {
    unsigned a2 = above;
    for (int i = 15; i > (bb & 15); --i) a2 += loc[i];
    sB2[row] = bb;
    sREM[row] = (int)(K2 - a2);
  }
}

// ---- fallback gather: only if the B1 buffer overflowed (expected never) ----
__global__ void k_gather_fb(const float* __restrict__ u0s, const float* __restrict__ u0t,
                            const double* __restrict__ tabs,
                            const int* __restrict__ sB1, const int* __restrict__ sB2,
                            const unsigned int* __restrict__ bcnt,
                            unsigned int* __restrict__ gcnt,
                            unsigned long long* __restrict__ gkey, unsigned int* __restrict__ gidx) {
  int row = blockIdx.x / FB_CHUNKS, chunk = blockIdx.x % FB_CHUNKS;
  if (bcnt[row] <= BCAP) return;
  __shared__ double tb[112];
  for (int i = threadIdx.x; i < 112; i += blockDim.x) tb[i] = tabs[row * 112 + i];
  __syncthreads();
  int b1 = sB1[row];
  unsigned b2 = (unsigned)sB2[row];
  int m = row >> 5, b = row & 31;
  const float4* u0 = reinterpret_cast<const float4*>((m ? u0t : u0s) + (size_t)b * NTOK);
  int base = chunk * (F4_PER_ROW / FB_CHUNKS);
  for (int it = 0; it < F4_PER_ROW / FB_CHUNKS / NTHR; ++it) {
    int f4 = base + it * NTHR + threadIdx.x;
    float4 x = u0[f4];
    int n0 = f4 * 4;
    int w0 = n0 & 31, hh = (n0 >> 5) & 31, tt = (n0 >> 10) & 31, vv = n0 >> 15;
    double g = tb[vv] * tb[16 + tt] * tb[48 + hh];
    double ks[4];
    ks[0] = clamp64((double)x.x) * (g * tb[80 + w0 + 0]);
    ks[1] = clamp64((double)x.y) * (g * tb[80 + w0 + 1]);
    ks[2] = clamp64((double)x.z) * (g * tb[80 + w0 + 2]);
    ks[3] = clamp64((double)x.w) * (g * tb[80 + w0 + 3]);
#pragma unroll
    for (int c = 0; c < 4; ++c) {
      unsigned long long kb = (unsigned long long)__double_as_longlong(ks[c]);
      if (bucket16(kb) == b1 && (((unsigned)(kb >> 39)) & 0xFFFu) == b2) {
        unsigned pos = atomicAdd(&gcnt[row], 1u);
        if (pos < GCAP) {
          gkey[(size_t)row * GCAP + pos] = kb;
          gidx[(size_t)row * GCAP + pos] = (unsigned)(n0 + c);
        }
      }
    }
  }
}

// ---- select: filter buffer by B2 (typ. a few elements), sort, pick REM-th ----
__global__ __launch_bounds__(1024) void k_select(const unsigned long long* __restrict__ bk,
                                                 const unsigned int* __restrict__ bi,
                                                 const unsigned int* __restrict__ bcnt,
                                                 const unsigned long long* __restrict__ gkey,
                                                 const unsigned int* __restrict__ gidx,
                                                 const unsigned int* __restrict__ gcnt,
                                                 const int* __restrict__ sB2,
                                                 const int* __restrict__ sREM,
                                                 unsigned long long* __restrict__ sT,
                                                 int* __restrict__ sIT) {
  __shared__ unsigned long long k[GCAP];
  __shared__ unsigned int ix[GCAP];
  __shared__ unsigned int lcnt;
  int row = blockIdx.x;
  if (threadIdx.x == 0) lcnt = 0;
  __syncthreads();
  unsigned cnt1 = bcnt[row];
  unsigned n_r;
  if (cnt1 <= BCAP) {
    unsigned b2 = (unsigned)sB2[row];
    for (unsigned i = threadIdx.x; i < cnt1; i += blockDim.x) {
      unsigned long long kb = bk[(size_t)row * BCAP + i];
      if ((((unsigned)(kb >> 39)) & 0xFFFu) == b2) {
        unsigned p = atomicAdd(&lcnt, 1u);
        if (p < GCAP) { k[p] = kb; ix[p] = bi[(size_t)row * BCAP + i]; }
      }
    }
    __syncthreads();
    n_r = lcnt; if (n_r > GCAP) n_r = GCAP;
  } else {
    n_r = gcnt[row];
    if (n_r > GCAP) n_r = GCAP;
    for (unsigned i = threadIdx.x; i < n_r; i += blockDim.x) {
      k[i] = gkey[(size_t)row * GCAP + i];
      ix[i] = gidx[(size_t)row * GCAP + i];
    }
    __syncthreads();
  }
  unsigned n2 = 2;
  while (n2 < n_r) n2 <<= 1;
  for (unsigned i = threadIdx.x; i < n2; i += blockDim.x) {
    if (i >= n_r) { k[i] = 0ULL; ix[i] = 0xFFFFFFFFu; }
  }
  __syncthreads();
  for (unsigned kk = 2; kk <= n2; kk <<= 1) {
    for (unsigned j = kk >> 1; j > 0; j >>= 1) {
      for (int i = threadIdx.x; i < (int)n2; i += blockDim.x) {
        int pj = i ^ (int)j;
        if (pj > i) {
          unsigned long long k1 = k[i], k2 = k[pj];
          unsigned i1 = ix[i], i2 = ix[pj];
          bool bef = (k1 > k2) || (k1 == k2 && i1 < i2);
          bool dirAsc = ((i & (int)kk) == 0);
          if (bef != dirAsc) { k[i] = k2; k[pj] = k1; ix[i] = i2; ix[pj] = i1; }
        }
      }
      __syncthreads();
    }
  }
  if (threadIdx.x == 0) {
    int rem = sREM[row];
    if (rem < 1) rem = 1;
    if ((unsigned)rem > n_r) rem = (int)n_r;
    sT[row] = k[rem - 1];
    sIT[row] = (int)ix[rem - 1];
  }
}

// ---- final: write masks as int32 0/1 ----
__global__ void k_final(const float* __restrict__ u0s, const float* __restrict__ u0t,
                        const double* __restrict__ tabs,
                        const unsigned long long* __restrict__ sT, const int* __restrict__ sIT,
                        int* __restrict__ out) {
  __shared__ double tb[112];
  int row = blockIdx.x / CHUNKS, chunk = blockIdx.x % CHUNKS;
  for (int i = threadIdx.x; i < 112; i += blockDim.x) tb[i] = tabs[row * 112 + i];
  __syncthreads();
  unsigned long long T = sT[row];
  int IT = sIT[row];
  int m = row >> 5, b = row & 31;
  const float4* u0 = reinterpret_cast<const float4*>((m ? u0t : u0s) + (size_t)b * NTOK);
  int4* o = reinterpret_cast<int4*>(out + (size_t)row * NTOK);
  int base = chunk * F4_PER_CHUNK;
  for (int it = 0; it < F4_PER_THR; ++it) {
    int f4 = base + it * NTHR + threadIdx.x;
    float4 x = u0[f4];
    int n0 = f4 * 4;
    int w0 = n0 & 31, hh = (n0 >> 5) & 31, tt = (n0 >> 10) & 31, vv = n0 >> 15;
    double g = tb[vv] * tb[16 + tt] * tb[48 + hh];
    unsigned long long kb0 = (unsigned long long)__double_as_longlong(clamp64((double)x.x) * (g * tb[80 + w0 + 0]));
    unsigned long long kb1 = (unsigned long long)__double_as_longlong(clamp64((double)x.y) * (g * tb[80 + w0 + 1]));
    unsigned long long kb2 = (unsigned long long)__double_as_longlong(clamp64((double)x.z) * (g * tb[80 + w0 + 2]));
    unsigned long long kb3 = (unsigned long long)__double_as_longlong(clamp64((double)x.w) * (g * tb[80 + w0 + 3]));
    int4 r;
    r.x = (kb0 > T || (kb0 == T && (n0 + 0) <= IT)) ? 1 : 0;
    r.y = (kb1 > T || (kb1 == T && (n0 + 1) <= IT)) ? 1 : 0;
    r.z = (kb2 > T || (kb2 == T && (n0 + 2) <= IT)) ? 1 : 0;
    r.w = (kb3 > T || (kb3 == T && (n0 + 3) <= IT)) ? 1 : 0;
    o[f4] = r;
  }
}

extern "C" void kernel_launch(void* const* d_in, const int* in_sizes, int n_in,
                              void* d_out, int out_size, void* d_ws, size_t ws_size,
                              hipStream_t stream) {
  const float* comps = (const float*)d_in[0];
  const float* urs   = (const float*)d_in[1];
  const float* urt   = (const float*)d_in[2];
  const float* u0s   = (const float*)d_in[3];
  const float* u0t   = (const float*)d_in[4];
  const float* uvs   = (const float*)d_in[5];
  const float* uts   = (const float*)d_in[6];
  const float* uhs   = (const float*)d_in[7];
  const float* uws   = (const float*)d_in[8];
  const float* uvt   = (const float*)d_in[9];
  const float* utt   = (const float*)d_in[10];
  const float* uht   = (const float*)d_in[11];
  const float* uwt   = (const float*)d_in[12];
  const int*   idxp  = (const int*)d_in[13];
  int* out = (int*)d_out;

  char* ws = (char*)d_ws;
  unsigned int*       h16  = (unsigned int*)(ws + OFF_H16);
  unsigned int*       gh2  = (unsigned int*)(ws + OFF_H2);
  int*                sB1  = (int*)(ws + OFF_B1);
  int*                sCG  = (int*)(ws + OFF_CG);
  int*                sB2  = (int*)(ws + OFF_B2);
  int*                sREM = (int*)(ws + OFF_REM);
  int*                sIT  = (int*)(ws + OFF_IT);
  unsigned int*       bcnt = (unsigned int*)(ws + OFF_BCNT);
  unsigned int*       gcnt = (unsigned int*)(ws + OFF_GCNT);
  unsigned long long* sT   = (unsigned long long*)(ws + OFF_T);
  double*             tabs = (double*)(ws + OFF_TAB);
  unsigned long long* bk   = (unsigned long long*)(ws + OFF_BK);
  unsigned int*       bi   = (unsigned int*)(ws + OFF_BI);
  unsigned long long* gkey = (unsigned long long*)(ws + OFF_GKEY);
  unsigned int*       gidx = (unsigned int*)(ws + OFF_GIDX);

  // zero hists + counters (ws is poisoned 0xAA before every call)
  hipMemsetAsync(d_ws, 0, OFF_ZERO_END, stream);

  k_tables<<<1, 256, 0, stream>>>(comps, idxp, uvs, uts, uhs, uws, uvt, utt, uht, uwt, tabs);
  k_hist16<<<ROWS * CHUNKS, NTHR, 0, stream>>>(u0s, u0t, tabs, h16);
  k_scan16<<<ROWS, 256, 0, stream>>>(h16, urs, urt, sB1, sCG);
  k_gather2<<<ROWS * CHUNKS, NTHR, 0, stream>>>(u0s, u0t, tabs, sB1, gh2, bcnt, bk, bi);
  k_scan2<<<ROWS, 256, 0, stream>>>(gh2, urs, urt, sCG, sB2, sREM);
  k_gather_fb<<<ROWS * FB_CHUNKS, NTHR, 0, stream>>>(u0s, u0t, tabs, sB1, sB2, bcnt, gcnt, gkey, gidx);
  k_select<<<ROWS, 1024, 0, stream>>>(bk, bi, bcnt, gkey, gidx, gcnt, sB2, sREM, sT, sIT);
  k_final<<<ROWS * CHUNKS, NTHR, 0, stream>>>(u0s, u0t, tabs, sT, sIT, out);
}

// Round 10
// 368.377 us; speedup vs baseline: 1.7839x; 1.0050x over previous
//
#include <hip/hip_runtime.h>
#include <stdint.h>

#define NTOK 524288
#define ROWS 64
#define CHUNKS 64
#define NTHR 256
#define F4_PER_ROW (NTOK / 4)                 // 131072
#define F4_PER_CHUNK (F4_PER_ROW / CHUNKS)    // 2048
#define F4_PER_THR (F4_PER_CHUNK / NTHR)      // 8
#define NB1 2048                              // 16-bit level-1: exp[960,1024) x 32
#define B1BASE 30720                          // 960 << 5
#define BCAP 65536                            // per-row B1 buffer cap (c(B1) <= ~12K proven)
#define GCAP 8192
#define STAGECAP 512                          // per-block LDS staging (expected ~107)

// ---- workspace layout (bytes) ----
#define OFF_H16  0u
#define OFF_B1   (OFF_H16 + ROWS * NB1 * 4u)          // 512 KiB
#define OFF_CG   (OFF_B1 + 256u)
#define OFF_BCNT (OFF_CG + 256u)
#define OFF_IT   (OFF_BCNT + 256u)
#define OFF_T    (OFF_IT + 256u)                      // 8-aligned (525312)
#define OFF_ZERO_END (OFF_T + 512u)
#define OFF_TAB  OFF_ZERO_END                         // 64*112 doubles (8-aligned)
#define OFF_BK   (OFF_TAB + ROWS * 112u * 8u)         // 32 MiB keys
#define OFF_BI   (OFF_BK + (size_t)ROWS * BCAP * 8u)  // 16 MiB idx

__device__ __forceinline__ double clamp64(double x) {
  return fmin(fmax(x, 1.0e-3), 1.0 - 1.0e-3);
}

// K exactly as reference: float32 clamp, float32 multiply, truncate
__device__ __forceinline__ unsigned compute_K(float ur) {
  float urf = fminf(fmaxf(ur, 1.0e-3f), 1.0f - 1.0e-3f);
  return (unsigned)(int)(urf * (float)NTOK);
}

// level-1 bucket: bits [62:47] = exponent(11b) + mantissa-top-5, rebased
__device__ __forceinline__ int bucket16(unsigned long long kb) {
  int b = (int)(unsigned)(kb >> 47) - B1BASE;
  return b < 0 ? 0 : (b > NB1 - 1 ? NB1 - 1 : b);
}

// ---- per-row dim factor tables: F = clamp(u)^(1/alpha), f64 ----
__global__ void k_tables(const float* __restrict__ comps, const int* __restrict__ idxp,
                         const float* __restrict__ uvs, const float* __restrict__ uts,
                         const float* __restrict__ uhs, const float* __restrict__ uws,
                         const float* __restrict__ uvt, const float* __restrict__ utt,
                         const float* __restrict__ uht, const float* __restrict__ uwt,
                         double* __restrict__ tabs) {
  int idx = idxp[0];
  double alpha[4];
  for (int d = 0; d < 4; ++d) alpha[d] = (double)comps[idx * 4 + d];
  for (int i = threadIdx.x; i < ROWS * 112; i += blockDim.x) {
    int row = i / 112, j = i % 112;
    int m = row >> 5, b = row & 31;
    int d, jj, dsz;
    if (j < 16)      { d = 0; jj = j;      dsz = 16; }
    else if (j < 48) { d = 1; jj = j - 16; dsz = 32; }
    else if (j < 80) { d = 2; jj = j - 48; dsz = 32; }
    else             { d = 3; jj = j - 80; dsz = 32; }
    const float* u;
    if (m == 0) u = (d == 0) ? uvs : (d == 1) ? uts : (d == 2) ? uhs : uws;
    else        u = (d == 0) ? uvt : (d == 1) ? utt : (d == 2) ? uht : uwt;
    double x = clamp64((double)u[b * dsz + jj]);
    double a = alpha[d];
    double f;
    if (a == 1.0)      f = x;
    else if (a == 2.0) f = sqrt(x);
    else if (a == 4.0) f = sqrt(sqrt(x));
    else               f = pow(x, 1.0 / a);
    tabs[row * 112 + j] = f;
  }
}

// ---- pass 1: 2048-bucket level-1 histogram ----
__global__ void k_hist16(const float* __restrict__ u0s, const float* __restrict__ u0t,
                         const double* __restrict__ tabs, unsigned int* __restrict__ h16) {
  __shared__ double tb[112];
  __shared__ unsigned int h[NB1];
  int row = blockIdx.x / CHUNKS, chunk = blockIdx.x % CHUNKS;
  for (int i = threadIdx.x; i < 112; i += blockDim.x) tb[i] = tabs[row * 112 + i];
  for (int i = threadIdx.x; i < NB1; i += blockDim.x) h[i] = 0;
  __syncthreads();
  int m = row >> 5, b = row & 31;
  const float4* u0 = reinterpret_cast<const float4*>((m ? u0t : u0s) + (size_t)b * NTOK);
  int base = chunk * F4_PER_CHUNK;
  for (int it = 0; it < F4_PER_THR; ++it) {
    int f4 = base + it * NTHR + threadIdx.x;
    float4 x = u0[f4];
    int n0 = f4 * 4;
    int w0 = n0 & 31, hh = (n0 >> 5) & 31, tt = (n0 >> 10) & 31, vv = n0 >> 15;
    double g = tb[vv] * tb[16 + tt] * tb[48 + hh];
    double k0 = clamp64((double)x.x) * (g * tb[80 + w0 + 0]);
    double k1 = clamp64((double)x.y) * (g * tb[80 + w0 + 1]);
    double k2 = clamp64((double)x.z) * (g * tb[80 + w0 + 2]);
    double k3 = clamp64((double)x.w) * (g * tb[80 + w0 + 3]);
    atomicAdd(&h[bucket16((unsigned long long)__double_as_longlong(k0))], 1u);
    atomicAdd(&h[bucket16((unsigned long long)__double_as_longlong(k1))], 1u);
    atomicAdd(&h[bucket16((unsigned long long)__double_as_longlong(k2))], 1u);
    atomicAdd(&h[bucket16((unsigned long long)__double_as_longlong(k3))], 1u);
  }
  __syncthreads();
  for (int i = threadIdx.x; i < NB1; i += blockDim.x) {
    unsigned c = h[i];
    if (c) atomicAdd(&h16[row * NB1 + i], c);
  }
}

// ---- scan level-1: one block/row; B1 = bucket holding K-th largest; CG = count above ----
__global__ __launch_bounds__(256) void k_scan16(const unsigned int* __restrict__ h16,
                                                const float* __restrict__ urs,
                                                const float* __restrict__ urt,
                                                int* __restrict__ sB1, int* __restrict__ sCG) {
  __shared__ unsigned suf[256];
  __shared__ int best;
  int row = blockIdx.x;
  int t = threadIdx.x;
  const unsigned* h = h16 + row * NB1;
  unsigned loc[8]; unsigned own = 0;
#pragma unroll
  for (int i = 0; i < 8; ++i) { loc[i] = h[t * 8 + i]; own += loc[i]; }
  suf[t] = own;
  if (t == 0) best = -1;
  __syncthreads();
  for (int off = 1; off < 256; off <<= 1) {
    unsigned add = (t + off < 256) ? suf[t + off] : 0u;
    __syncthreads();
    suf[t] += add;
    __syncthreads();
  }
  int m = row >> 5;
  unsigned K = compute_K(m ? urt[0] : urs[0]);
  unsigned above = suf[t] - own;
  int cand = -1;
  unsigned cum = above;
  for (int i = 7; i >= 0; --i) {
    if (cum + loc[i] >= K) { cand = t * 8 + i; break; }
    cum += loc[i];
  }
  if (cand >= 0) atomicMax(&best, cand);
  __syncthreads();
  int bb = best;
  if (bb >= 0 && (bb >> 3) == t) {
    unsigned cg = above;
    for (int i = 7; i > (bb & 7); --i) cg += loc[i];
    sB1[row] = bb;
    sCG[row] = (int)cg;
  }
}

// ---- pass 2: lean gather of B1 members (no in-pass histogram) ----
__global__ void k_gather2(const float* __restrict__ u0s, const float* __restrict__ u0t,
                          const double* __restrict__ tabs, const int* __restrict__ sB1,
                          unsigned int* __restrict__ bcnt,
                          unsigned long long* __restrict__ bk, unsigned int* __restrict__ bi) {
  __shared__ double tb[112];
  __shared__ unsigned long long sk[STAGECAP];
  __shared__ unsigned int si[STAGECAP];
  __shared__ unsigned int scnt, sbase;
  int row = blockIdx.x / CHUNKS, chunk = blockIdx.x % CHUNKS;
  for (int i = threadIdx.x; i < 112; i += blockDim.x) tb[i] = tabs[row * 112 + i];
  if (threadIdx.x == 0) scnt = 0;
  __syncthreads();
  int b1 = sB1[row];
  int m = row >> 5, b = row & 31;
  const float4* u0 = reinterpret_cast<const float4*>((m ? u0t : u0s) + (size_t)b * NTOK);
  int base = chunk * F4_PER_CHUNK;
  for (int it = 0; it < F4_PER_THR; ++it) {
    int f4 = base + it * NTHR + threadIdx.x;
    float4 x = u0[f4];
    int n0 = f4 * 4;
    int w0 = n0 & 31, hh = (n0 >> 5) & 31, tt = (n0 >> 10) & 31, vv = n0 >> 15;
    double g = tb[vv] * tb[16 + tt] * tb[48 + hh];
    double ks[4];
    ks[0] = clamp64((double)x.x) * (g * tb[80 + w0 + 0]);
    ks[1] = clamp64((double)x.y) * (g * tb[80 + w0 + 1]);
    ks[2] = clamp64((double)x.z) * (g * tb[80 + w0 + 2]);
    ks[3] = clamp64((double)x.w) * (g * tb[80 + w0 + 3]);
#pragma unroll
    for (int c = 0; c < 4; ++c) {
      unsigned long long kb = (unsigned long long)__double_as_longlong(ks[c]);
      if (bucket16(kb) == b1) {
        unsigned p = atomicAdd(&scnt, 1u);          // LDS atomic
        if (p < STAGECAP) { sk[p] = kb; si[p] = (unsigned)(n0 + c); }
        else {  // statistically never
          unsigned gp = atomicAdd(&bcnt[row], 1u);
          if (gp < BCAP) {
            bk[(size_t)row * BCAP + gp] = kb;
            bi[(size_t)row * BCAP + gp] = (unsigned)(n0 + c);
          }
        }
      }
    }
  }
  __syncthreads();
  unsigned nst = scnt; if (nst > STAGECAP) nst = STAGECAP;
  if (threadIdx.x == 0) sbase = atomicAdd(&bcnt[row], nst);  // ONE reservation/block
  __syncthreads();
  unsigned bs = sbase;
  for (unsigned i = threadIdx.x; i < nst; i += blockDim.x) {
    unsigned gp = bs + i;
    if (gp < BCAP) {
      bk[(size_t)row * BCAP + gp] = sk[i];
      bi[(size_t)row * BCAP + gp] = si[i];
    }
  }
}

// ---- pick: per row, hist [50:39] from buffer -> B2/REM -> filter -> sort -> T/IT ----
__global__ __launch_bounds__(256) void k_pick(const unsigned long long* __restrict__ bk,
                                              const unsigned int* __restrict__ bi,
                                              const unsigned int* __restrict__ bcnt,
                                              const float* __restrict__ urs,
                                              const float* __restrict__ urt,
                                              const int* __restrict__ sCG,
                                              unsigned long long* __restrict__ sT,
                                              int* __restrict__ sIT) {
  __shared__ unsigned int h[4096];
  __shared__ unsigned suf[256];
  __shared__ int best;
  __shared__ unsigned long long kk[GCAP];
  __shared__ unsigned int ixx[GCAP];
  __shared__ unsigned int lcnt;
  int row = blockIdx.x;
  int t = threadIdx.x;
  unsigned cnt = bcnt[row]; if (cnt > BCAP) cnt = BCAP;
  const unsigned long long* rbk = bk + (size_t)row * BCAP;
  const unsigned int* rbi = bi + (size_t)row * BCAP;
  for (int i = t; i < 4096; i += 256) h[i] = 0;
  if (t == 0) { best = -1; lcnt = 0; }
  __syncthreads();
  // phase A: refine histogram from the gathered buffer
  for (unsigned i = t; i < cnt; i += 256)
    atomicAdd(&h[(unsigned)(rbk[i] >> 39) & 0xFFFu], 1u);
  __syncthreads();
  // suffix scan over 4096 buckets (16 per thread)
  unsigned loc[16]; unsigned own = 0;
#pragma unroll
  for (int i = 0; i < 16; ++i) { loc[i] = h[t * 16 + i]; own += loc[i]; }
  suf[t] = own;
  __syncthreads();
  for (int off = 1; off < 256; off <<= 1) {
    unsigned add = (t + off < 256) ? suf[t + off] : 0u;
    __syncthreads();
    suf[t] += add;
    __syncthreads();
  }
  int m = row >> 5;
  unsigned K = compute_K(m ? urt[0] : urs[0]);
  unsigned K2 = K - (unsigned)sCG[row];   // >= 1
  unsigned above = suf[t] - own;
  int cand = -1;
  unsigned cum = above;
  for (int i = 15; i >= 0; --i) {
    if (cum + loc[i] >= K2) { cand = t * 16 + i; break; }
    cum += loc[i];
  }
  if (cand >= 0) atomicMax(&best, cand);
  __syncthreads();
  int b2 = best;
  // REM: recompute "above b2" on the owning thread, broadcast via shared
  __shared__ unsigned sharedRem;
  if (b2 >= 0 && (b2 >> 4) == t) {
    unsigned a2 = above;
    for (int i = 15; i > (b2 & 15); --i) a2 += loc[i];
    sharedRem = K2 - a2;
  }
  __syncthreads();
  unsigned rem = sharedRem;
  // phase B: filter buffer by b2 into LDS
  for (unsigned i = t; i < cnt; i += 256) {
    unsigned long long kb = rbk[i];
    if (((unsigned)(kb >> 39) & 0xFFFu) == (unsigned)b2) {
      unsigned p = atomicAdd(&lcnt, 1u);
      if (p < GCAP) { kk[p] = kb; ixx[p] = rbi[i]; }
    }
  }
  __syncthreads();
  unsigned n_r = lcnt; if (n_r > GCAP) n_r = GCAP;
  unsigned n2 = 2;
  while (n2 < n_r) n2 <<= 1;
  for (unsigned i = t; i < n2; i += 256)
    if (i >= n_r) { kk[i] = 0ULL; ixx[i] = 0xFFFFFFFFu; }
  __syncthreads();
  for (unsigned kstep = 2; kstep <= n2; kstep <<= 1) {
    for (unsigned j = kstep >> 1; j > 0; j >>= 1) {
      for (int i = t; i < (int)n2; i += 256) {
        int pj = i ^ (int)j;
        if (pj > i) {
          unsigned long long k1 = kk[i], k2v = kk[pj];
          unsigned i1 = ixx[i], i2 = ixx[pj];
          bool bef = (k1 > k2v) || (k1 == k2v && i1 < i2);
          bool dirAsc = ((i & (int)kstep) == 0);
          if (bef != dirAsc) { kk[i] = k2v; kk[pj] = k1; ixx[i] = i2; ixx[pj] = i1; }
        }
      }
      __syncthreads();
    }
  }
  if (t == 0) {
    int r = (int)rem;
    if (r < 1) r = 1;
    if ((unsigned)r > n_r) r = (int)n_r;
    sT[row] = kk[r - 1];
    sIT[row] = (int)ixx[r - 1];
  }
}

// ---- final: write masks as int32 0/1 ----
__global__ void k_final(const float* __restrict__ u0s, const float* __restrict__ u0t,
                        const double* __restrict__ tabs,
                        const unsigned long long* __restrict__ sT, const int* __restrict__ sIT,
                        int* __restrict__ out) {
  __shared__ double tb[112];
  int row = blockIdx.x / CHUNKS, chunk = blockIdx.x % CHUNKS;
  for (int i = threadIdx.x; i < 112; i += blockDim.x) tb[i] = tabs[row * 112 + i];
  __syncthreads();
  unsigned long long T = sT[row];
  int IT = sIT[row];
  int m = row >> 5, b = row & 31;
  const float4* u0 = reinterpret_cast<const float4*>((m ? u0t : u0s) + (size_t)b * NTOK);
  int4* o = reinterpret_cast<int4*>(out + (size_t)row * NTOK);
  int base = chunk * F4_PER_CHUNK;
  for (int it = 0; it < F4_PER_THR; ++it) {
    int f4 = base + it * NTHR + threadIdx.x;
    float4 x = u0[f4];
    int n0 = f4 * 4;
    int w0 = n0 & 31, hh = (n0 >> 5) & 31, tt = (n0 >> 10) & 31, vv = n0 >> 15;
    double g = tb[vv] * tb[16 + tt] * tb[48 + hh];
    unsigned long long kb0 = (unsigned long long)__double_as_longlong(clamp64((double)x.x) * (g * tb[80 + w0 + 0]));
    unsigned long long kb1 = (unsigned long long)__double_as_longlong(clamp64((double)x.y) * (g * tb[80 + w0 + 1]));
    unsigned long long kb2 = (unsigned long long)__double_as_longlong(clamp64((double)x.z) * (g * tb[80 + w0 + 2]));
    unsigned long long kb3 = (unsigned long long)__double_as_longlong(clamp64((double)x.w) * (g * tb[80 + w0 + 3]));
    int4 r;
    r.x = (kb0 > T || (kb0 == T && (n0 + 0) <= IT)) ? 1 : 0;
    r.y = (kb1 > T || (kb1 == T && (n0 + 1) <= IT)) ? 1 : 0;
    r.z = (kb2 > T || (kb2 == T && (n0 + 2) <= IT)) ? 1 : 0;
    r.w = (kb3 > T || (kb3 == T && (n0 + 3) <= IT)) ? 1 : 0;
    o[f4] = r;
  }
}

extern "C" void kernel_launch(void* const* d_in, const int* in_sizes, int n_in,
                              void* d_out, int out_size, void* d_ws, size_t ws_size,
                              hipStream_t stream) {
  const float* comps = (const float*)d_in[0];
  const float* urs   = (const float*)d_in[1];
  const float* urt   = (const float*)d_in[2];
  const float* u0s   = (const float*)d_in[3];
  const float* u0t   = (const float*)d_in[4];
  const float* uvs   = (const float*)d_in[5];
  const float* uts   = (const float*)d_in[6];
  const float* uhs   = (const float*)d_in[7];
  const float* uws   = (const float*)d_in[8];
  const float* uvt   = (const float*)d_in[9];
  const float* utt   = (const float*)d_in[10];
  const float* uht   = (const float*)d_in[11];
  const float* uwt   = (const float*)d_in[12];
  const int*   idxp  = (const int*)d_in[13];
  int* out = (int*)d_out;

  char* ws = (char*)d_ws;
  unsigned int*       h16  = (unsigned int*)(ws + OFF_H16);
  int*                sB1  = (int*)(ws + OFF_B1);
  int*                sCG  = (int*)(ws + OFF_CG);
  unsigned int*       bcnt = (unsigned int*)(ws + OFF_BCNT);
  int*                sIT  = (int*)(ws + OFF_IT);
  unsigned long long* sT   = (unsigned long long*)(ws + OFF_T);
  double*             tabs = (double*)(ws + OFF_TAB);
  unsigned long long* bk   = (unsigned long long*)(ws + OFF_BK);
  unsigned int*       bi   = (unsigned int*)(ws + OFF_BI);

  // zero hist + counters (ws is poisoned 0xAA before every call)
  hipMemsetAsync(d_ws, 0, OFF_ZERO_END, stream);

  k_tables<<<1, 256, 0, stream>>>(comps, idxp, uvs, uts, uhs, uws, uvt, utt, uht, uwt, tabs);
  k_hist16<<<ROWS * CHUNKS, NTHR, 0, stream>>>(u0s, u0t, tabs, h16);
  k_scan16<<<ROWS, 256, 0, stream>>>(h16, urs, urt, sB1, sCG);
  k_gather2<<<ROWS * CHUNKS, NTHR, 0, stream>>>(u0s, u0t, tabs, sB1, bcnt, bk, bi);
  k_pick<<<ROWS, 256, 0, stream>>>(bk, bi, bcnt, urs, urt, sCG, sT, sIT);
  k_final<<<ROWS * CHUNKS, NTHR, 0, stream>>>(u0s, u0t, tabs, sT, sIT, out);
}

// Round 11
// 342.226 us; speedup vs baseline: 1.9202x; 1.0764x over previous
//
#include <hip/hip_runtime.h>
#include <stdint.h>

#define NTOK 524288
#define ROWS 64
#define CHUNKS 64
#define CHUNKS_H 32
#define NTHR 256
#define F4_PER_ROW (NTOK / 4)                   // 131072
#define F4_PER_CHUNK (F4_PER_ROW / CHUNKS)      // 2048
#define F4_PER_THR (F4_PER_CHUNK / NTHR)        // 8
#define F4_PER_CHUNK_H (F4_PER_ROW / CHUNKS_H)  // 4096
#define F4_PER_THR_H (F4_PER_CHUNK_H / NTHR)    // 16
#define NB1 2048                                // level-1: exp x mantissa-top-5
#define B1BASE 30720                            // 960 << 5
#define BCAP 65536                              // per-row B1 buffer cap (c(B1) <= ~12K proven)
#define GCAP 8192
#define STAGECAP 512                            // per-block LDS staging (expected ~110-190)

// ---- workspace layout (bytes) ----
#define OFF_H16  0u
#define OFF_B1   (OFF_H16 + ROWS * NB1 * 4u)          // 512 KiB
#define OFF_CG   (OFF_B1 + 256u)
#define OFF_BCNT (OFF_CG + 256u)
#define OFF_IT   (OFF_BCNT + 256u)
#define OFF_T    (OFF_IT + 256u)                      // 8-aligned
#define OFF_ZERO_END (OFF_T + 512u)
#define OFF_TAB  OFF_ZERO_END                         // 64*112 doubles
#define OFF_BK   (OFF_TAB + ROWS * 112u * 8u)         // 32 MiB keys
#define OFF_BI   (OFF_BK + (size_t)ROWS * BCAP * 8u)  // 16 MiB idx

__device__ __forceinline__ double clamp64(double x) {
  return fmin(fmax(x, 1.0e-3), 1.0 - 1.0e-3);
}

// K exactly as reference: float32 clamp, float32 multiply, truncate
__device__ __forceinline__ unsigned compute_K(float ur) {
  float urf = fminf(fmaxf(ur, 1.0e-3f), 1.0f - 1.0e-3f);
  return (unsigned)(int)(urf * (float)NTOK);
}

// level-1 bucket: bits [62:47], rebased; monotone non-decreasing in key
__device__ __forceinline__ int bucket16(unsigned long long kb) {
  int b = (int)(unsigned)(kb >> 47) - B1BASE;
  return b < 0 ? 0 : (b > NB1 - 1 ? NB1 - 1 : b);
}

// ---- per-row dim factor tables: F = clamp(u)^(1/alpha), f64 ----
__global__ void k_tables(const float* __restrict__ comps, const int* __restrict__ idxp,
                         const float* __restrict__ uvs, const float* __restrict__ uts,
                         const float* __restrict__ uhs, const float* __restrict__ uws,
                         const float* __restrict__ uvt, const float* __restrict__ utt,
                         const float* __restrict__ uht, const float* __restrict__ uwt,
                         double* __restrict__ tabs) {
  int idx = idxp[0];
  double alpha[4];
  for (int d = 0; d < 4; ++d) alpha[d] = (double)comps[idx * 4 + d];
  for (int i = threadIdx.x; i < ROWS * 112; i += blockDim.x) {
    int row = i / 112, j = i % 112;
    int m = row >> 5, b = row & 31;
    int d, jj, dsz;
    if (j < 16)      { d = 0; jj = j;      dsz = 16; }
    else if (j < 48) { d = 1; jj = j - 16; dsz = 32; }
    else if (j < 80) { d = 2; jj = j - 48; dsz = 32; }
    else             { d = 3; jj = j - 80; dsz = 32; }
    const float* u;
    if (m == 0) u = (d == 0) ? uvs : (d == 1) ? uts : (d == 2) ? uhs : uws;
    else        u = (d == 0) ? uvt : (d == 1) ? utt : (d == 2) ? uht : uwt;
    double x = clamp64((double)u[b * dsz + jj]);
    double a = alpha[d];
    double f;
    if (a == 1.0)      f = x;
    else if (a == 2.0) f = sqrt(x);
    else if (a == 4.0) f = sqrt(sqrt(x));
    else               f = pow(x, 1.0 / a);
    tabs[row * 112 + j] = f;
  }
}

// ---- pass 1: 2048-bucket level-1 histogram (CHUNKS_H=32: fewer global flushes) ----
__global__ void k_hist16(const float* __restrict__ u0s, const float* __restrict__ u0t,
                         const double* __restrict__ tabs, unsigned int* __restrict__ h16) {
  __shared__ double tb[112];
  __shared__ unsigned int h[NB1];
  int row = blockIdx.x / CHUNKS_H, chunk = blockIdx.x % CHUNKS_H;
  for (int i = threadIdx.x; i < 112; i += blockDim.x) tb[i] = tabs[row * 112 + i];
  for (int i = threadIdx.x; i < NB1; i += blockDim.x) h[i] = 0;
  __syncthreads();
  int m = row >> 5, b = row & 31;
  const float4* u0 = reinterpret_cast<const float4*>((m ? u0t : u0s) + (size_t)b * NTOK);
  int base = chunk * F4_PER_CHUNK_H;
  for (int it = 0; it < F4_PER_THR_H; ++it) {
    int f4 = base + it * NTHR + threadIdx.x;
    float4 x = u0[f4];
    int n0 = f4 * 4;
    int w0 = n0 & 31, hh = (n0 >> 5) & 31, tt = (n0 >> 10) & 31, vv = n0 >> 15;
    double g = tb[vv] * tb[16 + tt] * tb[48 + hh];
    double k0 = clamp64((double)x.x) * (g * tb[80 + w0 + 0]);
    double k1 = clamp64((double)x.y) * (g * tb[80 + w0 + 1]);
    double k2 = clamp64((double)x.z) * (g * tb[80 + w0 + 2]);
    double k3 = clamp64((double)x.w) * (g * tb[80 + w0 + 3]);
    atomicAdd(&h[bucket16((unsigned long long)__double_as_longlong(k0))], 1u);
    atomicAdd(&h[bucket16((unsigned long long)__double_as_longlong(k1))], 1u);
    atomicAdd(&h[bucket16((unsigned long long)__double_as_longlong(k2))], 1u);
    atomicAdd(&h[bucket16((unsigned long long)__double_as_longlong(k3))], 1u);
  }
  __syncthreads();
  for (int i = threadIdx.x; i < NB1; i += blockDim.x) {
    unsigned c = h[i];
    if (c) atomicAdd(&h16[row * NB1 + i], c);
  }
}

// ---- scan level-1: one block/row; B1 = bucket holding K-th largest; CG = count above ----
__global__ __launch_bounds__(256) void k_scan16(const unsigned int* __restrict__ h16,
                                                const float* __restrict__ urs,
                                                const float* __restrict__ urt,
                                                int* __restrict__ sB1, int* __restrict__ sCG) {
  __shared__ unsigned suf[256];
  __shared__ int best;
  int row = blockIdx.x;
  int t = threadIdx.x;
  const unsigned* h = h16 + row * NB1;
  unsigned loc[8]; unsigned own = 0;
#pragma unroll
  for (int i = 0; i < 8; ++i) { loc[i] = h[t * 8 + i]; own += loc[i]; }
  suf[t] = own;
  if (t == 0) best = -1;
  __syncthreads();
  for (int off = 1; off < 256; off <<= 1) {
    unsigned add = (t + off < 256) ? suf[t + off] : 0u;
    __syncthreads();
    suf[t] += add;
    __syncthreads();
  }
  int m = row >> 5;
  unsigned K = compute_K(m ? urt[0] : urs[0]);
  unsigned above = suf[t] - own;
  int cand = -1;
  unsigned cum = above;
  for (int i = 7; i >= 0; --i) {
    if (cum + loc[i] >= K) { cand = t * 8 + i; break; }
    cum += loc[i];
  }
  if (cand >= 0) atomicMax(&best, cand);
  __syncthreads();
  int bb = best;
  if (bb >= 0 && (bb >> 3) == t) {
    unsigned cg = above;
    for (int i = 7; i > (bb & 7); --i) cg += loc[i];
    sB1[row] = bb;
    sCG[row] = (int)cg;
  }
}

// ---- pass 2: write provisional mask (bucket>B1 -> 1, else 0) + gather B1 members ----
__global__ void k_gatherw(const float* __restrict__ u0s, const float* __restrict__ u0t,
                          const double* __restrict__ tabs, const int* __restrict__ sB1,
                          unsigned int* __restrict__ bcnt,
                          unsigned long long* __restrict__ bk, unsigned int* __restrict__ bi,
                          int* __restrict__ out) {
  __shared__ double tb[112];
  __shared__ unsigned long long sk[STAGECAP];
  __shared__ unsigned int si[STAGECAP];
  __shared__ unsigned int scnt, sbase;
  int row = blockIdx.x / CHUNKS, chunk = blockIdx.x % CHUNKS;
  for (int i = threadIdx.x; i < 112; i += blockDim.x) tb[i] = tabs[row * 112 + i];
  if (threadIdx.x == 0) scnt = 0;
  __syncthreads();
  int b1 = sB1[row];
  int m = row >> 5, b = row & 31;
  const float4* u0 = reinterpret_cast<const float4*>((m ? u0t : u0s) + (size_t)b * NTOK);
  int4* o = reinterpret_cast<int4*>(out + (size_t)row * NTOK);
  int base = chunk * F4_PER_CHUNK;
  for (int it = 0; it < F4_PER_THR; ++it) {
    int f4 = base + it * NTHR + threadIdx.x;
    float4 x = u0[f4];
    int n0 = f4 * 4;
    int w0 = n0 & 31, hh = (n0 >> 5) & 31, tt = (n0 >> 10) & 31, vv = n0 >> 15;
    double g = tb[vv] * tb[16 + tt] * tb[48 + hh];
    double ks[4];
    ks[0] = clamp64((double)x.x) * (g * tb[80 + w0 + 0]);
    ks[1] = clamp64((double)x.y) * (g * tb[80 + w0 + 1]);
    ks[2] = clamp64((double)x.z) * (g * tb[80 + w0 + 2]);
    ks[3] = clamp64((double)x.w) * (g * tb[80 + w0 + 3]);
    int r[4];
#pragma unroll
    for (int c = 0; c < 4; ++c) {
      unsigned long long kb = (unsigned long long)__double_as_longlong(ks[c]);
      int bkt = bucket16(kb);
      r[c] = (bkt > b1) ? 1 : 0;           // members (==b1) provisionally 0, fixed later
      if (bkt == b1) {
        unsigned p = atomicAdd(&scnt, 1u);  // LDS atomic
        if (p < STAGECAP) { sk[p] = kb; si[p] = (unsigned)(n0 + c); }
        else {  // statistically never
          unsigned gp = atomicAdd(&bcnt[row], 1u);
          if (gp < BCAP) {
            bk[(size_t)row * BCAP + gp] = kb;
            bi[(size_t)row * BCAP + gp] = (unsigned)(n0 + c);
          }
        }
      }
    }
    int4 rv; rv.x = r[0]; rv.y = r[1]; rv.z = r[2]; rv.w = r[3];
    o[f4] = rv;
  }
  __syncthreads();
  unsigned nst = scnt; if (nst > STAGECAP) nst = STAGECAP;
  if (threadIdx.x == 0) sbase = atomicAdd(&bcnt[row], nst);  // ONE reservation/block
  __syncthreads();
  unsigned bs = sbase;
  for (unsigned i = threadIdx.x; i < nst; i += blockDim.x) {
    unsigned gp = bs + i;
    if (gp < BCAP) {
      bk[(size_t)row * BCAP + gp] = sk[i];
      bi[(size_t)row * BCAP + gp] = si[i];
    }
  }
}

// ---- pick: per row, hist [50:39] from buffer -> B2/REM -> filter -> sort -> T/IT ----
__global__ __launch_bounds__(256) void k_pick(const unsigned long long* __restrict__ bk,
                                              const unsigned int* __restrict__ bi,
                                              const unsigned int* __restrict__ bcnt,
                                              const float* __restrict__ urs,
                                              const float* __restrict__ urt,
                                              const int* __restrict__ sCG,
                                              unsigned long long* __restrict__ sT,
                                              int* __restrict__ sIT) {
  __shared__ unsigned int h[4096];
  __shared__ unsigned suf[256];
  __shared__ int best;
  __shared__ unsigned long long kk[GCAP];
  __shared__ unsigned int ixx[GCAP];
  __shared__ unsigned int lcnt;
  __shared__ unsigned sharedRem;
  int row = blockIdx.x;
  int t = threadIdx.x;
  unsigned cnt = bcnt[row]; if (cnt > BCAP) cnt = BCAP;
  const unsigned long long* rbk = bk + (size_t)row * BCAP;
  const unsigned int* rbi = bi + (size_t)row * BCAP;
  for (int i = t; i < 4096; i += 256) h[i] = 0;
  if (t == 0) { best = -1; lcnt = 0; }
  __syncthreads();
  for (unsigned i = t; i < cnt; i += 256)
    atomicAdd(&h[(unsigned)(rbk[i] >> 39) & 0xFFFu], 1u);
  __syncthreads();
  unsigned loc[16]; unsigned own = 0;
#pragma unroll
  for (int i = 0; i < 16; ++i) { loc[i] = h[t * 16 + i]; own += loc[i]; }
  suf[t] = own;
  __syncthreads();
  for (int off = 1; off < 256; off <<= 1) {
    unsigned add = (t + off < 256) ? suf[t + off] : 0u;
    __syncthreads();
    suf[t] += add;
    __syncthreads();
  }
  int m = row >> 5;
  unsigned K = compute_K(m ? urt[0] : urs[0]);
  unsigned K2 = K - (unsigned)sCG[row];   // >= 1
  unsigned above = suf[t] - own;
  int cand = -1;
  unsigned cum = above;
  for (int i = 15; i >= 0; --i) {
    if (cum + loc[i] >= K2) { cand = t * 16 + i; break; }
    cum += loc[i];
  }
  if (cand >= 0) atomicMax(&best, cand);
  __syncthreads();
  int b2 = best;
  if (b2 >= 0 && (b2 >> 4) == t) {
    unsigned a2 = above;
    for (int i = 15; i > (b2 & 15); --i) a2 += loc[i];
    sharedRem = K2 - a2;
  }
  __syncthreads();
  unsigned rem = sharedRem;
  for (unsigned i = t; i < cnt; i += 256) {
    unsigned long long kb = rbk[i];
    if (((unsigned)(kb >> 39) & 0xFFFu) == (unsigned)b2) {
      unsigned p = atomicAdd(&lcnt, 1u);
      if (p < GCAP) { kk[p] = kb; ixx[p] = rbi[i]; }
    }
  }
  __syncthreads();
  unsigned n_r = lcnt; if (n_r > GCAP) n_r = GCAP;
  unsigned n2 = 2;
  while (n2 < n_r) n2 <<= 1;
  for (unsigned i = t; i < n2; i += 256)
    if (i >= n_r) { kk[i] = 0ULL; ixx[i] = 0xFFFFFFFFu; }
  __syncthreads();
  for (unsigned kstep = 2; kstep <= n2; kstep <<= 1) {
    for (unsigned j = kstep >> 1; j > 0; j >>= 1) {
      for (int i = t; i < (int)n2; i += 256) {
        int pj = i ^ (int)j;
        if (pj > i) {
          unsigned long long k1 = kk[i], k2v = kk[pj];
          unsigned i1 = ixx[i], i2 = ixx[pj];
          bool bef = (k1 > k2v) || (k1 == k2v && i1 < i2);
          bool dirAsc = ((i & (int)kstep) == 0);
          if (bef != dirAsc) { kk[i] = k2v; kk[pj] = k1; ixx[i] = i2; ixx[pj] = i1; }
        }
      }
      __syncthreads();
    }
  }
  if (t == 0) {
    int r = (int)rem;
    if (r < 1) r = 1;
    if ((unsigned)r > n_r) r = (int)n_r;
    sT[row] = kk[r - 1];
    sIT[row] = (int)ixx[r - 1];
  }
}

// ---- fixup: write final 0/1 for the gathered B1 members only (~7-12K/row) ----
__global__ __launch_bounds__(256) void k_fixup(const unsigned long long* __restrict__ bk,
                                               const unsigned int* __restrict__ bi,
                                               const unsigned int* __restrict__ bcnt,
                                               const unsigned long long* __restrict__ sT,
                                               const int* __restrict__ sIT,
                                               int* __restrict__ out) {
  int row = blockIdx.x;
  unsigned cnt = bcnt[row]; if (cnt > BCAP) cnt = BCAP;
  unsigned long long T = sT[row];
  int IT = sIT[row];
  const unsigned long long* rbk = bk + (size_t)row * BCAP;
  const unsigned int* rbi = bi + (size_t)row * BCAP;
  int* o = out + (size_t)row * NTOK;
  for (unsigned i = threadIdx.x; i < cnt; i += blockDim.x) {
    unsigned long long kb = rbk[i];
    unsigned idx = rbi[i];
    o[idx] = (kb > T || (kb == T && (int)idx <= IT)) ? 1 : 0;
  }
}

extern "C" void kernel_launch(void* const* d_in, const int* in_sizes, int n_in,
                              void* d_out, int out_size, void* d_ws, size_t ws_size,
                              hipStream_t stream) {
  const float* comps = (const float*)d_in[0];
  const float* urs   = (const float*)d_in[1];
  const float* urt   = (const float*)d_in[2];
  const float* u0s   = (const float*)d_in[3];
  const float* u0t   = (const float*)d_in[4];
  const float* uvs   = (const float*)d_in[5];
  const float* uts   = (const float*)d_in[6];
  const float* uhs   = (const float*)d_in[7];
  const float* uws   = (const float*)d_in[8];
  const float* uvt   = (const float*)d_in[9];
  const float* utt   = (const float*)d_in[10];
  const float* uht   = (const float*)d_in[11];
  const float* uwt   = (const float*)d_in[12];
  const int*   idxp  = (const int*)d_in[13];
  int* out = (int*)d_out;

  char* ws = (char*)d_ws;
  unsigned int*       h16  = (unsigned int*)(ws + OFF_H16);
  int*                sB1  = (int*)(ws + OFF_B1);
  int*                sCG  = (int*)(ws + OFF_CG);
  unsigned int*       bcnt = (unsigned int*)(ws + OFF_BCNT);
  int*                sIT  = (int*)(ws + OFF_IT);
  unsigned long long* sT   = (unsigned long long*)(ws + OFF_T);
  double*             tabs = (double*)(ws + OFF_TAB);
  unsigned long long* bk   = (unsigned long long*)(ws + OFF_BK);
  unsigned int*       bi   = (unsigned int*)(ws + OFF_BI);

  // zero hist + counters (ws is poisoned 0xAA before every call)
  hipMemsetAsync(d_ws, 0, OFF_ZERO_END, stream);

  k_tables<<<1, 256, 0, stream>>>(comps, idxp, uvs, uts, uhs, uws, uvt, utt, uht, uwt, tabs);
  k_hist16<<<ROWS * CHUNKS_H, NTHR, 0, stream>>>(u0s, u0t, tabs, h16);
  k_scan16<<<ROWS, 256, 0, stream>>>(h16, urs, urt, sB1, sCG);
  k_gatherw<<<ROWS * CHUNKS, NTHR, 0, stream>>>(u0s, u0t, tabs, sB1, bcnt, bk, bi, out);
  k_pick<<<ROWS, 256, 0, stream>>>(bk, bi, bcnt, urs, urt, sCG, sT, sIT);
  k_fixup<<<ROWS, 256, 0, stream>>>(bk, bi, bcnt, sT, sIT, out);
}

// Round 12
// 322.288 us; speedup vs baseline: 2.0390x; 1.0619x over previous
//
#include <hip/hip_runtime.h>
#include <stdint.h>

#define NTOK 524288
#define ROWS 64
#define CHUNKS 64
#define CHUNKS_H 32
#define NTHR 256
#define F4_PER_ROW (NTOK / 4)                   // 131072
#define F4_PER_CHUNK (F4_PER_ROW / CHUNKS)      // 2048
#define F4_PER_THR (F4_PER_CHUNK / NTHR)        // 8
#define F4_PER_CHUNK_H (F4_PER_ROW / CHUNKS_H)  // 4096
#define F4_PER_THR_H (F4_PER_CHUNK_H / NTHR)    // 16
#define NB1 2048                                // level-1: exp x mantissa-top-5
#define NB1R 2052                               // replicated-copy stride (bank skew)
#define B1BASE 30720                            // 960 << 5
#define BCAP 65536                              // per-row B1 buffer cap (c(B1) <= ~12K)
#define GCAP 8192
#define STAGECAP 512                            // per-block LDS staging (expected ~110-190)

// ---- workspace layout (bytes) ----
#define OFF_H16  0u
#define OFF_B1   (OFF_H16 + ROWS * NB1 * 4u)          // 512 KiB
#define OFF_CG   (OFF_B1 + 256u)
#define OFF_BCNT (OFF_CG + 256u)
#define OFF_ZERO_END (OFF_BCNT + 256u)
#define OFF_BK   ((OFF_ZERO_END + 7u) & ~7u)          // 32 MiB keys
#define OFF_BI   (OFF_BK + (size_t)ROWS * BCAP * 8u)  // 16 MiB idx

__device__ __forceinline__ double clamp64(double x) {
  return fmin(fmax(x, 1.0e-3), 1.0 - 1.0e-3);
}

// K exactly as reference: float32 clamp, float32 multiply, truncate
__device__ __forceinline__ unsigned compute_K(float ur) {
  float urf = fminf(fmaxf(ur, 1.0e-3f), 1.0f - 1.0e-3f);
  return (unsigned)(int)(urf * (float)NTOK);
}

// level-1 bucket: bits [62:47], rebased; monotone non-decreasing in key
__device__ __forceinline__ int bucket16(unsigned long long kb) {
  int b = (int)(unsigned)(kb >> 47) - B1BASE;
  return b < 0 ? 0 : (b > NB1 - 1 ? NB1 - 1 : b);
}

// block-local table build: tb[112] = clamp(u)^(1/alpha) for this row, f64.
// Deterministic f64 ops -> bit-identical across kernels.
__device__ __forceinline__ void build_tb(double* tb, int row,
                                         const float* comps, const int* idxp,
                                         const float* uvs, const float* uts,
                                         const float* uhs, const float* uws,
                                         const float* uvt, const float* utt,
                                         const float* uht, const float* uwt) {
  int m = row >> 5, b = row & 31;
  int idx = idxp[0];
  for (int j = threadIdx.x; j < 112; j += blockDim.x) {
    int d, jj, dsz;
    if (j < 16)      { d = 0; jj = j;      dsz = 16; }
    else if (j < 48) { d = 1; jj = j - 16; dsz = 32; }
    else if (j < 80) { d = 2; jj = j - 48; dsz = 32; }
    else             { d = 3; jj = j - 80; dsz = 32; }
    const float* u;
    if (m == 0) u = (d == 0) ? uvs : (d == 1) ? uts : (d == 2) ? uhs : uws;
    else        u = (d == 0) ? uvt : (d == 1) ? utt : (d == 2) ? uht : uwt;
    double x = clamp64((double)u[b * dsz + jj]);
    double a = (double)comps[idx * 4 + d];
    double f;
    if (a == 1.0)      f = x;
    else if (a == 2.0) f = sqrt(x);
    else if (a == 4.0) f = sqrt(sqrt(x));
    else               f = pow(x, 1.0 / a);
    tb[j] = f;
  }
}

// ---- pass 1: 2048-bucket level-1 histogram, 2-way replicated LDS copies ----
__global__ void k_hist16(const float* __restrict__ u0s, const float* __restrict__ u0t,
                         const float* __restrict__ comps, const int* __restrict__ idxp,
                         const float* __restrict__ uvs, const float* __restrict__ uts,
                         const float* __restrict__ uhs, const float* __restrict__ uws,
                         const float* __restrict__ uvt, const float* __restrict__ utt,
                         const float* __restrict__ uht, const float* __restrict__ uwt,
                         unsigned int* __restrict__ h16) {
  __shared__ double tb[112];
  __shared__ unsigned int h[2 * NB1R];
  int row = blockIdx.x / CHUNKS_H, chunk = blockIdx.x % CHUNKS_H;
  build_tb(tb, row, comps, idxp, uvs, uts, uhs, uws, uvt, utt, uht, uwt);
  for (int i = threadIdx.x; i < 2 * NB1R; i += blockDim.x) h[i] = 0;
  __syncthreads();
  unsigned rep = (threadIdx.x & 1) * NB1R;
  int m = row >> 5, b = row & 31;
  const float4* u0 = reinterpret_cast<const float4*>((m ? u0t : u0s) + (size_t)b * NTOK);
  int base = chunk * F4_PER_CHUNK_H;
  for (int it = 0; it < F4_PER_THR_H; ++it) {
    int f4 = base + it * NTHR + threadIdx.x;
    float4 x = u0[f4];
    int n0 = f4 * 4;
    int w0 = n0 & 31, hh = (n0 >> 5) & 31, tt = (n0 >> 10) & 31, vv = n0 >> 15;
    double g = tb[vv] * tb[16 + tt] * tb[48 + hh];
    double k0 = clamp64((double)x.x) * (g * tb[80 + w0 + 0]);
    double k1 = clamp64((double)x.y) * (g * tb[80 + w0 + 1]);
    double k2 = clamp64((double)x.z) * (g * tb[80 + w0 + 2]);
    double k3 = clamp64((double)x.w) * (g * tb[80 + w0 + 3]);
    atomicAdd(&h[rep + bucket16((unsigned long long)__double_as_longlong(k0))], 1u);
    atomicAdd(&h[rep + bucket16((unsigned long long)__double_as_longlong(k1))], 1u);
    atomicAdd(&h[rep + bucket16((unsigned long long)__double_as_longlong(k2))], 1u);
    atomicAdd(&h[rep + bucket16((unsigned long long)__double_as_longlong(k3))], 1u);
  }
  __syncthreads();
  for (int i = threadIdx.x; i < NB1; i += blockDim.x) {
    unsigned c = h[i] + h[NB1R + i];
    if (c) atomicAdd(&h16[row * NB1 + i], c);
  }
}

// ---- scan level-1: one block/row; B1 = bucket holding K-th largest; CG = count above ----
__global__ __launch_bounds__(256) void k_scan16(const unsigned int* __restrict__ h16,
                                                const float* __restrict__ urs,
                                                const float* __restrict__ urt,
                                                int* __restrict__ sB1, int* __restrict__ sCG) {
  __shared__ unsigned suf[256];
  __shared__ int best;
  int row = blockIdx.x;
  int t = threadIdx.x;
  const unsigned* h = h16 + row * NB1;
  unsigned loc[8]; unsigned own = 0;
#pragma unroll
  for (int i = 0; i < 8; ++i) { loc[i] = h[t * 8 + i]; own += loc[i]; }
  suf[t] = own;
  if (t == 0) best = -1;
  __syncthreads();
  for (int off = 1; off < 256; off <<= 1) {
    unsigned add = (t + off < 256) ? suf[t + off] : 0u;
    __syncthreads();
    suf[t] += add;
    __syncthreads();
  }
  int m = row >> 5;
  unsigned K = compute_K(m ? urt[0] : urs[0]);
  unsigned above = suf[t] - own;
  int cand = -1;
  unsigned cum = above;
  for (int i = 7; i >= 0; --i) {
    if (cum + loc[i] >= K) { cand = t * 8 + i; break; }
    cum += loc[i];
  }
  if (cand >= 0) atomicMax(&best, cand);
  __syncthreads();
  int bb = best;
  if (bb >= 0 && (bb >> 3) == t) {
    unsigned cg = above;
    for (int i = 7; i > (bb & 7); --i) cg += loc[i];
    sB1[row] = bb;
    sCG[row] = (int)cg;
  }
}

// ---- pass 2: provisional mask write (bucket>B1 -> 1) + gather B1 members ----
__global__ void k_gatherw(const float* __restrict__ u0s, const float* __restrict__ u0t,
                          const float* __restrict__ comps, const int* __restrict__ idxp,
                          const float* __restrict__ uvs, const float* __restrict__ uts,
                          const float* __restrict__ uhs, const float* __restrict__ uws,
                          const float* __restrict__ uvt, const float* __restrict__ utt,
                          const float* __restrict__ uht, const float* __restrict__ uwt,
                          const int* __restrict__ sB1,
                          unsigned int* __restrict__ bcnt,
                          unsigned long long* __restrict__ bk, unsigned int* __restrict__ bi,
                          int* __restrict__ out) {
  __shared__ double tb[112];
  __shared__ unsigned long long sk[STAGECAP];
  __shared__ unsigned int si[STAGECAP];
  __shared__ unsigned int scnt, sbase;
  int row = blockIdx.x / CHUNKS, chunk = blockIdx.x % CHUNKS;
  build_tb(tb, row, comps, idxp, uvs, uts, uhs, uws, uvt, utt, uht, uwt);
  if (threadIdx.x == 0) scnt = 0;
  __syncthreads();
  int b1 = sB1[row];
  int m = row >> 5, b = row & 31;
  const float4* u0 = reinterpret_cast<const float4*>((m ? u0t : u0s) + (size_t)b * NTOK);
  int4* o = reinterpret_cast<int4*>(out + (size_t)row * NTOK);
  int base = chunk * F4_PER_CHUNK;
  for (int it = 0; it < F4_PER_THR; ++it) {
    int f4 = base + it * NTHR + threadIdx.x;
    float4 x = u0[f4];
    int n0 = f4 * 4;
    int w0 = n0 & 31, hh = (n0 >> 5) & 31, tt = (n0 >> 10) & 31, vv = n0 >> 15;
    double g = tb[vv] * tb[16 + tt] * tb[48 + hh];
    double ks[4];
    ks[0] = clamp64((double)x.x) * (g * tb[80 + w0 + 0]);
    ks[1] = clamp64((double)x.y) * (g * tb[80 + w0 + 1]);
    ks[2] = clamp64((double)x.z) * (g * tb[80 + w0 + 2]);
    ks[3] = clamp64((double)x.w) * (g * tb[80 + w0 + 3]);
    int r[4];
#pragma unroll
    for (int c = 0; c < 4; ++c) {
      unsigned long long kb = (unsigned long long)__double_as_longlong(ks[c]);
      int bkt = bucket16(kb);
      r[c] = (bkt > b1) ? 1 : 0;            // members (==b1) provisionally 0, fixed in k_pick
      if (bkt == b1) {
        unsigned p = atomicAdd(&scnt, 1u);  // LDS atomic
        if (p < STAGECAP) { sk[p] = kb; si[p] = (unsigned)(n0 + c); }
        else {  // statistically never
          unsigned gp = atomicAdd(&bcnt[row], 1u);
          if (gp < BCAP) {
            bk[(size_t)row * BCAP + gp] = kb;
            bi[(size_t)row * BCAP + gp] = (unsigned)(n0 + c);
          }
        }
      }
    }
    int4 rv; rv.x = r[0]; rv.y = r[1]; rv.z = r[2]; rv.w = r[3];
    o[f4] = rv;
  }
  __syncthreads();
  unsigned nst = scnt; if (nst > STAGECAP) nst = STAGECAP;
  if (threadIdx.x == 0) sbase = atomicAdd(&bcnt[row], nst);  // ONE reservation/block
  __syncthreads();
  unsigned bs = sbase;
  for (unsigned i = threadIdx.x; i < nst; i += blockDim.x) {
    unsigned gp = bs + i;
    if (gp < BCAP) {
      bk[(size_t)row * BCAP + gp] = sk[i];
      bi[(size_t)row * BCAP + gp] = si[i];
    }
  }
}

// ---- pick+fixup: hist [50:39] -> B2/REM -> filter -> sort -> T/IT -> scatter-fix members ----
__global__ __launch_bounds__(256) void k_pick(const unsigned long long* __restrict__ bk,
                                              const unsigned int* __restrict__ bi,
                                              const unsigned int* __restrict__ bcnt,
                                              const float* __restrict__ urs,
                                              const float* __restrict__ urt,
                                              const int* __restrict__ sCG,
                                              int* __restrict__ out) {
  __shared__ unsigned int h[4096];
  __shared__ unsigned suf[256];
  __shared__ int best;
  __shared__ unsigned long long kk[GCAP];
  __shared__ unsigned int ixx[GCAP];
  __shared__ unsigned int lcnt;
  __shared__ unsigned sharedRem;
  __shared__ unsigned long long shT;
  __shared__ int shIT;
  int row = blockIdx.x;
  int t = threadIdx.x;
  unsigned cnt = bcnt[row]; if (cnt > BCAP) cnt = BCAP;
  const unsigned long long* rbk = bk + (size_t)row * BCAP;
  const unsigned int* rbi = bi + (size_t)row * BCAP;
  for (int i = t; i < 4096; i += 256) h[i] = 0;
  if (t == 0) { best = -1; lcnt = 0; }
  __syncthreads();
  for (unsigned i = t; i < cnt; i += 256)
    atomicAdd(&h[(unsigned)(rbk[i] >> 39) & 0xFFFu], 1u);
  __syncthreads();
  unsigned loc[16]; unsigned own = 0;
#pragma unroll
  for (int i = 0; i < 16; ++i) { loc[i] = h[t * 16 + i]; own += loc[i]; }
  suf[t] = own;
  __syncthreads();
  for (int off = 1; off < 256; off <<= 1) {
    unsigned add = (t + off < 256) ? suf[t + off] : 0u;
    __syncthreads();
    suf[t] += add;
    __syncthreads();
  }
  int m = row >> 5;
  unsigned K = compute_K(m ? urt[0] : urs[0]);
  unsigned K2 = K - (unsigned)sCG[row];   // >= 1
  unsigned above = suf[t] - own;
  int cand = -1;
  unsigned cum = above;
  for (int i = 15; i >= 0; --i) {
    if (cum + loc[i] >= K2) { cand = t * 16 + i; break; }
    cum += loc[i];
  }
  if (cand >= 0) atomicMax(&best, cand);
  __syncthreads();
  int b2 = best;
  if (b2 >= 0 && (b2 >> 4) == t) {
    unsigned a2 = above;
    for (int i = 15; i > (b2 & 15); --i) a2 += loc[i];
    sharedRem = K2 - a2;
  }
  __syncthreads();
  unsigned rem = sharedRem;
  for (unsigned i = t; i < cnt; i += 256) {
    unsigned long long kb = rbk[i];
    if (((unsigned)(kb >> 39) & 0xFFFu) == (unsigned)b2) {
      unsigned p = atomicAdd(&lcnt, 1u);
      if (p < GCAP) { kk[p] = kb; ixx[p] = rbi[i]; }
    }
  }
  __syncthreads();
  unsigned n_r = lcnt; if (n_r > GCAP) n_r = GCAP;
  unsigned n2 = 2;
  while (n2 < n_r) n2 <<= 1;
  for (unsigned i = t; i < n2; i += 256)
    if (i >= n_r) { kk[i] = 0ULL; ixx[i] = 0xFFFFFFFFu; }
  __syncthreads();
  for (unsigned kstep = 2; kstep <= n2; kstep <<= 1) {
    for (unsigned j = kstep >> 1; j > 0; j >>= 1) {
      for (int i = t; i < (int)n2; i += 256) {
        int pj = i ^ (int)j;
        if (pj > i) {
          unsigned long long k1 = kk[i], k2v = kk[pj];
          unsigned i1 = ixx[i], i2 = ixx[pj];
          bool bef = (k1 > k2v) || (k1 == k2v && i1 < i2);
          bool dirAsc = ((i & (int)kstep) == 0);
          if (bef != dirAsc) { kk[i] = k2v; kk[pj] = k1; ixx[i] = i2; ixx[pj] = i1; }
        }
      }
      __syncthreads();
    }
  }
  if (t == 0) {
    int r = (int)rem;
    if (r < 1) r = 1;
    if ((unsigned)r > n_r) r = (int)n_r;
    shT = kk[r - 1];
    shIT = (int)ixx[r - 1];
  }
  __syncthreads();
  // fixup: final 0/1 for the gathered B1 members (buffer is L2-hot)
  unsigned long long T = shT;
  int IT = shIT;
  int* o = out + (size_t)row * NTOK;
  for (unsigned i = t; i < cnt; i += 256) {
    unsigned long long kb = rbk[i];
    unsigned idx = rbi[i];
    o[idx] = (kb > T || (kb == T && (int)idx <= IT)) ? 1 : 0;
  }
}

extern "C" void kernel_launch(void* const* d_in, const int* in_sizes, int n_in,
                              void* d_out, int out_size, void* d_ws, size_t ws_size,
                              hipStream_t stream) {
  const float* comps = (const float*)d_in[0];
  const float* urs   = (const float*)d_in[1];
  const float* urt   = (const float*)d_in[2];
  const float* u0s   = (const float*)d_in[3];
  const float* u0t   = (const float*)d_in[4];
  const float* uvs   = (const float*)d_in[5];
  const float* uts   = (const float*)d_in[6];
  const float* uhs   = (const float*)d_in[7];
  const float* uws   = (const float*)d_in[8];
  const float* uvt   = (const float*)d_in[9];
  const float* utt   = (const float*)d_in[10];
  const float* uht   = (const float*)d_in[11];
  const float* uwt   = (const float*)d_in[12];
  const int*   idxp  = (const int*)d_in[13];
  int* out = (int*)d_out;

  char* ws = (char*)d_ws;
  unsigned int*       h16  = (unsigned int*)(ws + OFF_H16);
  int*                sB1  = (int*)(ws + OFF_B1);
  int*                sCG  = (int*)(ws + OFF_CG);
  unsigned int*       bcnt = (unsigned int*)(ws + OFF_BCNT);
  unsigned long long* bk   = (unsigned long long*)(ws + OFF_BK);
  unsigned int*       bi   = (unsigned int*)(ws + OFF_BI);

  // zero hist + counters (ws is poisoned 0xAA before every call)
  hipMemsetAsync(d_ws, 0, OFF_ZERO_END, stream);

  k_hist16<<<ROWS * CHUNKS_H, NTHR, 0, stream>>>(u0s, u0t, comps, idxp,
                                                 uvs, uts, uhs, uws, uvt, utt, uht, uwt, h16);
  k_scan16<<<ROWS, 256, 0, stream>>>(h16, urs, urt, sB1, sCG);
  k_gatherw<<<ROWS * CHUNKS, NTHR, 0, stream>>>(u0s, u0t, comps, idxp,
                                                uvs, uts, uhs, uws, uvt, utt, uht, uwt,
                                                sB1, bcnt, bk, bi, out);
  k_pick<<<ROWS, 256, 0, stream>>>(bk, bi, bcnt, urs, urt, sCG, out);
}